// Round 1
// baseline (3495.810 us; speedup 1.0000x reference)
//
#include <hip/hip_runtime.h>

#define HPIX 256
#define WPIX 256
#define TSX 16
#define TSY 16
#define FCH 256
#define BIGF 1000000000.0f
#define EPSF 1e-8f
#define MARGIN 0.125f

struct FaceRec {
  float x2, y2, a0, b0, a1, b1, inv, z0, z1, z2;
  float xmin, ymin, xmax, ymax;
};

// Compute the per-face record with EXACTLY the reference's op order (no FMA).
__device__ __forceinline__ FaceRec make_rec(const float* __restrict__ vb,
                                            const int* __restrict__ faces, int f) {
#pragma clang fp contract(off)
  FaceRec r;
  int i0 = faces[f * 3 + 0], i1 = faces[f * 3 + 1], i2 = faces[f * 3 + 2];
  float x0 = vb[i0 * 3 + 0], y0 = vb[i0 * 3 + 1], z0 = vb[i0 * 3 + 2];
  float x1 = vb[i1 * 3 + 0], y1 = vb[i1 * 3 + 1], z1 = vb[i1 * 3 + 2];
  float x2 = vb[i2 * 3 + 0], y2 = vb[i2 * 3 + 1], z2 = vb[i2 * 3 + 2];
  float px0 = x0 / z0, py0 = y0 / z0;
  float px1 = x1 / z1, py1 = y1 / z1;
  float px2 = x2 / z2, py2 = y2 / z2;
  float a0 = py1 - py2, b0 = px2 - px1;   // (y1-y2), (x2-x1)
  float a1 = py2 - py0, b1 = px0 - px2;   // (y2-y0), (x0-x2)
  float dy02 = py0 - py2;
  float denom = a0 * b1 + b0 * dy02;      // (y1-y2)*(x0-x2) + (x2-x1)*(y0-y2)
  bool nz = fabsf(denom) > EPSF;
  bool valid = nz && (z0 > 0.0f) && (z1 > 0.0f) && (z2 > 0.0f);
  r.x2 = px2; r.y2 = py2; r.a0 = a0; r.b0 = b0; r.a1 = a1; r.b1 = b1;
  r.inv = valid ? 1.0f / denom : 0.0f;    // invalid -> w0=w1=0, w2=1
  r.z0 = z0; r.z1 = z1;
  r.z2 = valid ? z2 : -1.0f;              // invalid -> depth=-1 -> fails depth>0
  if (valid) {
    r.xmin = fminf(px0, fminf(px1, px2)) - MARGIN;
    r.xmax = fmaxf(px0, fmaxf(px1, px2)) + MARGIN;
    r.ymin = fminf(py0, fminf(py1, py2)) - MARGIN;
    r.ymax = fmaxf(py0, fmaxf(py1, py2)) + MARGIN;
  } else {
    // empty bbox -> always tile-rejected (matches reference exclusion)
    r.xmin = 2.0f * BIGF; r.xmax = -2.0f * BIGF;
    r.ymin = 2.0f * BIGF; r.ymax = -2.0f * BIGF;
  }
  return r;
}

__global__ void prep_kernel(const float* __restrict__ verts,
                            const int* __restrict__ faces,
                            float4* __restrict__ recs, int V, int F, int NIMG) {
  int idx = blockIdx.x * blockDim.x + threadIdx.x;
  int total = NIMG * F;
  if (idx >= total) return;
  int n = idx / F, f = idx - n * F;
  FaceRec r = make_rec(verts + (size_t)n * V * 3, faces, f);
  float4* o = recs + (size_t)idx * 4;
  o[0] = make_float4(r.x2, r.y2, r.a0, r.b0);
  o[1] = make_float4(r.a1, r.b1, r.inv, r.z0);
  o[2] = make_float4(r.z1, r.z2, 0.0f, 0.0f);
  o[3] = make_float4(r.xmin, r.ymin, r.xmax, r.ymax);
}

// Epilogue: interpolate colors for the winning face, apply any-positive mask,
// write NCHW. Recomputes weights via make_rec -> bit-identical to inner loop.
__device__ __forceinline__ void emit_pixel(float* __restrict__ out,
    const float* __restrict__ vb, const float* __restrict__ colors,
    const int* __restrict__ faces, int n, int V, int C, int bestf,
    float cx, float cy, int row, int col) {
#pragma clang fp contract(off)
  float cv[8];
#pragma unroll
  for (int ch = 0; ch < 8; ++ch) cv[ch] = 0.0f;
  if (bestf >= 0) {
    int i0 = faces[bestf * 3 + 0], i1 = faces[bestf * 3 + 1], i2 = faces[bestf * 3 + 2];
    FaceRec r = make_rec(vb, faces, bestf);
    float bx = cx - r.x2, by = cy - r.y2;
    float w0 = (r.a0 * bx + r.b0 * by) * r.inv;
    float w1 = (r.a1 * bx + r.b1 * by) * r.inv;
    float w2 = 1.0f - w0 - w1;
    const float* c0 = colors + ((size_t)n * V + i0) * C;
    const float* c1 = colors + ((size_t)n * V + i1) * C;
    const float* c2 = colors + ((size_t)n * V + i2) * C;
    for (int ch = 0; ch < C && ch < 8; ++ch)
      cv[ch] = (w0 * c0[ch] + w1 * c1[ch]) + w2 * c2[ch];
  }
  bool anyp = false;
  for (int ch = 0; ch < C && ch < 8; ++ch) anyp = anyp || (cv[ch] > 0.0f);
  float m = anyp ? 1.0f : 0.0f;
  size_t base = (size_t)n * C * HPIX * WPIX + (size_t)row * WPIX + col;
  for (int ch = 0; ch < C && ch < 8; ++ch)
    out[base + (size_t)ch * HPIX * WPIX] = cv[ch] * m;
}

// Global-records path: per-face records are wave-uniform -> scalar loads.
__global__ __launch_bounds__(256) void raster_g(const float4* __restrict__ recs,
    const float* __restrict__ verts, const float* __restrict__ colors,
    const int* __restrict__ faces, float* __restrict__ out, int V, int F, int C) {
#pragma clang fp contract(off)
  const int n = blockIdx.z;
  const int tx = threadIdx.x, ty = threadIdx.y;
  const int col = blockIdx.x * TSX + tx;
  const int row = blockIdx.y * TSY + ty;
  const float cx = (float)col, cy = (float)row;
  const float tX0 = (float)(blockIdx.x * TSX), tX1 = tX0 + (float)(TSX - 1);
  const float tY0 = (float)(blockIdx.y * TSY), tY1 = tY0 + (float)(TSY - 1);
  const float4* rb = recs + (size_t)n * F * 4;
  float bestd = BIGF;
  int bestf = -1;
  for (int f = 0; f < F; ++f) {
    float4 bb = rb[f * 4 + 3];
    if (bb.x > tX1 || bb.z < tX0 || bb.y > tY1 || bb.w < tY0) continue;
    float4 A = rb[f * 4 + 0];
    float4 B = rb[f * 4 + 1];
    float4 Z = rb[f * 4 + 2];
    float bx = cx - A.x, by = cy - A.y;
    float w0 = (A.z * bx + A.w * by) * B.z;
    float w1 = (B.x * bx + B.y * by) * B.z;
    float w2 = 1.0f - w0 - w1;
    float depth = (w0 * B.w + w1 * Z.x) + w2 * Z.y;
    bool ok = (w0 >= 0.0f) && (w1 >= 0.0f) && (w2 >= 0.0f) && (depth > 0.0f);
    float d = ok ? depth : BIGF;
    if (d < bestd) { bestd = d; bestf = f; }   // strict < : first-min tie-break
  }
  emit_pixel(out, verts + (size_t)n * V * 3, colors, faces, n, V, C, bestf,
             cx, cy, row, col);
}

// Fallback (no workspace): stage records chunk-wise in LDS.
__global__ __launch_bounds__(256) void raster_l(const float* __restrict__ verts,
    const float* __restrict__ colors, const int* __restrict__ faces,
    float* __restrict__ out, int V, int F, int C) {
#pragma clang fp contract(off)
  __shared__ float4 sA[FCH], sB[FCH], sZ[FCH], sD[FCH];
  const int n = blockIdx.z;
  const int tx = threadIdx.x, ty = threadIdx.y;
  const int tid = ty * TSX + tx;
  const int col = blockIdx.x * TSX + tx;
  const int row = blockIdx.y * TSY + ty;
  const float cx = (float)col, cy = (float)row;
  const float tX0 = (float)(blockIdx.x * TSX), tX1 = tX0 + (float)(TSX - 1);
  const float tY0 = (float)(blockIdx.y * TSY), tY1 = tY0 + (float)(TSY - 1);
  const float* vb = verts + (size_t)n * V * 3;
  float bestd = BIGF;
  int bestf = -1;
  for (int base = 0; base < F; base += FCH) {
    int cnt = min(FCH, F - base);
    if (tid < cnt) {
      FaceRec r = make_rec(vb, faces, base + tid);
      sA[tid] = make_float4(r.x2, r.y2, r.a0, r.b0);
      sB[tid] = make_float4(r.a1, r.b1, r.inv, r.z0);
      sZ[tid] = make_float4(r.z1, r.z2, 0.0f, 0.0f);
      sD[tid] = make_float4(r.xmin, r.ymin, r.xmax, r.ymax);
    }
    __syncthreads();
    for (int j = 0; j < cnt; ++j) {
      float4 bb = sD[j];
      if (bb.x > tX1 || bb.z < tX0 || bb.y > tY1 || bb.w < tY0) continue;
      float4 A = sA[j];
      float4 B = sB[j];
      float4 Z = sZ[j];
      float bx = cx - A.x, by = cy - A.y;
      float w0 = (A.z * bx + A.w * by) * B.z;
      float w1 = (B.x * bx + B.y * by) * B.z;
      float w2 = 1.0f - w0 - w1;
      float depth = (w0 * B.w + w1 * Z.x) + w2 * Z.y;
      bool ok = (w0 >= 0.0f) && (w1 >= 0.0f) && (w2 >= 0.0f) && (depth > 0.0f);
      float d = ok ? depth : BIGF;
      if (d < bestd) { bestd = d; bestf = base + j; }
    }
    __syncthreads();
  }
  emit_pixel(out, vb, colors, faces, n, V, C, bestf, cx, cy, row, col);
}

extern "C" void kernel_launch(void* const* d_in, const int* in_sizes, int n_in,
                              void* d_out, int out_size, void* d_ws, size_t ws_size,
                              hipStream_t stream) {
  const float* verts = (const float*)d_in[0];
  const float* colors = (const float*)d_in[1];
  const int* faces = (const int*)d_in[2];
  float* out = (float*)d_out;
  long long s0 = in_sizes[0], s1 = in_sizes[1], s2 = in_sizes[2];
  int C = (int)((3LL * s1) / s0);           // colors N*V*C vs verts N*V*3
  if (C < 1) C = 1;
  int NC = out_size / (HPIX * WPIX);        // N*C
  int N = NC / C;
  if (N < 1) N = 1;
  int V = (int)(s0 / (3LL * N));
  int F = (int)(s2 / 3);

  dim3 block(TSX, TSY);
  dim3 grid(WPIX / TSX, HPIX / TSY, N);
  size_t need = (size_t)N * (size_t)F * 4 * sizeof(float4);
  if (d_ws != nullptr && ws_size >= need) {
    float4* recs = (float4*)d_ws;
    int total = N * F;
    prep_kernel<<<(total + 255) / 256, 256, 0, stream>>>(verts, faces, recs, V, F, N);
    raster_g<<<grid, block, 0, stream>>>(recs, verts, colors, faces, out, V, F, C);
  } else {
    raster_l<<<grid, block, 0, stream>>>(verts, colors, faces, out, V, F, C);
  }
}

// Round 2
// 1581.284 us; speedup vs baseline: 2.2107x; 2.2107x over previous
//
#include <hip/hip_runtime.h>

#define HPIX 256
#define WPIX 256
#define TSX 16
#define TSY 16
#define NTILE 256            // 16x16 tiles
#define FCH 256
#define SEG_BIN 8            // segments per tile bin (binned path)
#define SEG_FLAT 16          // segments over all faces (fallback path)
#define BIGF 1000000000.0f
#define EPSF 1e-8f
#define MARGIN 0.125f
#define HP_SLOP 0.5f
#define INIT_PACK 0xFFFFFFFFFFFFFFFFull

struct FaceRec {
  float x2, y2, a0, b0, a1, b1, inv, z0, z1, z2;
  float xmin, ymin, xmax, ymax;
};

// Compute the per-face record with EXACTLY the reference's op order (no FMA).
__device__ __forceinline__ FaceRec make_rec(const float* __restrict__ vb,
                                            const int* __restrict__ faces, int f) {
#pragma clang fp contract(off)
  FaceRec r;
  int i0 = faces[f * 3 + 0], i1 = faces[f * 3 + 1], i2 = faces[f * 3 + 2];
  float x0 = vb[i0 * 3 + 0], y0 = vb[i0 * 3 + 1], z0 = vb[i0 * 3 + 2];
  float x1 = vb[i1 * 3 + 0], y1 = vb[i1 * 3 + 1], z1 = vb[i1 * 3 + 2];
  float x2 = vb[i2 * 3 + 0], y2 = vb[i2 * 3 + 1], z2 = vb[i2 * 3 + 2];
  float px0 = x0 / z0, py0 = y0 / z0;
  float px1 = x1 / z1, py1 = y1 / z1;
  float px2 = x2 / z2, py2 = y2 / z2;
  float a0 = py1 - py2, b0 = px2 - px1;   // (y1-y2), (x2-x1)
  float a1 = py2 - py0, b1 = px0 - px2;   // (y2-y0), (x0-x2)
  float dy02 = py0 - py2;
  float denom = a0 * b1 + b0 * dy02;      // (y1-y2)*(x0-x2) + (x2-x1)*(y0-y2)
  bool nz = fabsf(denom) > EPSF;
  bool valid = nz && (z0 > 0.0f) && (z1 > 0.0f) && (z2 > 0.0f);
  r.x2 = px2; r.y2 = py2; r.a0 = a0; r.b0 = b0; r.a1 = a1; r.b1 = b1;
  r.inv = valid ? 1.0f / denom : 0.0f;
  r.z0 = z0; r.z1 = z1;
  r.z2 = valid ? z2 : -1.0f;              // invalid -> depth<0 -> fails depth>0
  if (valid) {
    r.xmin = fminf(px0, fminf(px1, px2)) - MARGIN;
    r.xmax = fmaxf(px0, fmaxf(px1, px2)) + MARGIN;
    r.ymin = fminf(py0, fminf(py1, py2)) - MARGIN;
    r.ymax = fmaxf(py0, fmaxf(py1, py2)) + MARGIN;
  } else {
    r.xmin = 2.0f * BIGF; r.xmax = -2.0f * BIGF;
    r.ymin = 2.0f * BIGF; r.ymax = -2.0f * BIGF;
  }
  return r;
}

__global__ void prep_kernel(const float* __restrict__ verts,
                            const int* __restrict__ faces,
                            float4* __restrict__ recs, int V, int F, int NIMG) {
  int idx = blockIdx.x * blockDim.x + threadIdx.x;
  int total = NIMG * F;
  if (idx >= total) return;
  int n = idx / F, f = idx - n * F;
  FaceRec r = make_rec(verts + (size_t)n * V * 3, faces, f);
  float4* o = recs + (size_t)idx * 4;
  o[0] = make_float4(r.x2, r.y2, r.a0, r.b0);
  o[1] = make_float4(r.a1, r.b1, r.inv, r.z0);
  o[2] = make_float4(r.z1, r.z2, 0.0f, 0.0f);
  o[3] = make_float4(r.xmin, r.ymin, r.xmax, r.ymax);
}

__global__ void init_kernel(unsigned long long* __restrict__ packed,
                            unsigned int* __restrict__ cursors,
                            int npix, int ncur) {
  int i = blockIdx.x * blockDim.x + threadIdx.x;
  if (i < npix) packed[i] = INIT_PACK;
  if (i < ncur) cursors[i] = 0u;
}

// Bin each face into the 16x16-px tiles it may touch: padded-bbox overlap
// + conservative half-plane reject (affine max over tile = max at corners;
// slop covers FP eval noise; skipped for sliver triangles |inv|>1).
__global__ void fill_kernel(const float4* __restrict__ recs,
                            unsigned int* __restrict__ cursors,
                            unsigned int* __restrict__ bins, int F, int NIMG) {
#pragma clang fp contract(off)
  int idx = blockIdx.x * blockDim.x + threadIdx.x;
  if (idx >= NIMG * F) return;
  int n = idx / F, f = idx - n * F;
  const float4* r = recs + (size_t)idx * 4;
  float4 A = r[0], B = r[1], D = r[3];
  int tx0 = (int)floorf(D.x * 0.0625f); tx0 = tx0 < 0 ? 0 : (tx0 > 15 ? 15 : tx0);
  int tx1 = (int)floorf(D.z * 0.0625f); tx1 = tx1 < 0 ? 0 : (tx1 > 15 ? 15 : tx1);
  int ty0 = (int)floorf(D.y * 0.0625f); ty0 = ty0 < 0 ? 0 : (ty0 > 15 ? 15 : ty0);
  int ty1 = (int)floorf(D.w * 0.0625f); ty1 = ty1 < 0 ? 0 : (ty1 > 15 ? 15 : ty1);
  if (D.x > (float)(WPIX - 1) + MARGIN || D.z < -MARGIN ||
      D.y > (float)(HPIX - 1) + MARGIN || D.w < -MARGIN) return;
  float inv = B.z;
  bool do_hp = fabsf(inv) <= 1.0f;
  for (int ty = ty0; ty <= ty1; ++ty) {
    for (int tx = tx0; tx <= tx1; ++tx) {
      bool keep = true;
      if (do_hp) {
        float X0 = (float)(tx * TSX), X1 = X0 + (float)(TSX - 1);
        float Y0 = (float)(ty * TSY), Y1 = Y0 + (float)(TSY - 1);
        float m0 = -3.0e38f, m1 = -3.0e38f, m2 = -3.0e38f;
#pragma unroll
        for (int c = 0; c < 4; ++c) {
          float ccx = (c & 1) ? X1 : X0;
          float ccy = (c & 2) ? Y1 : Y0;
          float bx = ccx - A.x, by = ccy - A.y;
          float w0 = (A.z * bx + A.w * by) * inv;
          float w1 = (B.x * bx + B.y * by) * inv;
          float w2 = 1.0f - w0 - w1;
          m0 = fmaxf(m0, w0); m1 = fmaxf(m1, w1); m2 = fmaxf(m2, w2);
        }
        keep = (m0 >= -HP_SLOP) && (m1 >= -HP_SLOP) && (m2 >= -HP_SLOP);
      }
      if (keep) {
        int t = ty * 16 + tx;
        unsigned int slot = atomicAdd(&cursors[n * NTILE + t], 1u);
        bins[((size_t)(n * NTILE + t)) * F + slot] = (unsigned int)f;
      }
    }
  }
}

// Exact per-pixel test, identical FP ops to the reference. Packed min gives
// min-depth with lowest-face-index tie-break (order-independent).
__device__ __forceinline__ void test_face(float4 A, float4 B, float4 Z, int f,
                                          float cx, float cy,
                                          unsigned long long& best) {
#pragma clang fp contract(off)
  float bx = cx - A.x, by = cy - A.y;
  float w0 = (A.z * bx + A.w * by) * B.z;
  float w1 = (B.x * bx + B.y * by) * B.z;
  float w2 = 1.0f - w0 - w1;
  float depth = (w0 * B.w + w1 * Z.x) + w2 * Z.y;
  bool ok = (w0 >= 0.0f) && (w1 >= 0.0f) && (w2 >= 0.0f) && (depth > 0.0f);
  if (ok) {
    unsigned long long p =
        ((unsigned long long)__float_as_uint(depth) << 32) | (unsigned int)f;
    best = p < best ? p : best;
  }
}

__global__ __launch_bounds__(256) void raster_binned(
    const float4* __restrict__ recs, const unsigned int* __restrict__ bins,
    const unsigned int* __restrict__ cursors,
    unsigned long long* __restrict__ packed, int F) {
  const int tx = threadIdx.x, ty = threadIdx.y;
  const int tileX = blockIdx.x, tileY = blockIdx.y;
  const int n = blockIdx.z / SEG_BIN, s = blockIdx.z % SEG_BIN;
  const int t = tileY * 16 + tileX;
  const int col = tileX * TSX + tx, row = tileY * TSY + ty;
  const float cx = (float)col, cy = (float)row;
  const float4* rb = recs + (size_t)n * F * 4;
  const unsigned int* bin = bins + ((size_t)(n * NTILE + t)) * F;
  const int cnt = (int)cursors[n * NTILE + t];
  unsigned long long best = INIT_PACK;
  for (int i = s; i < cnt; i += SEG_BIN) {
    int f = (int)bin[i];
    float4 A = rb[f * 4 + 0];
    float4 B = rb[f * 4 + 1];
    float4 Z = rb[f * 4 + 2];
    test_face(A, B, Z, f, cx, cy, best);
  }
  if (best != INIT_PACK)
    atomicMin(&packed[(size_t)n * (HPIX * WPIX) + row * WPIX + col], best);
}

// Fallback: no bins, segments over all faces with bbox reject.
__global__ __launch_bounds__(256) void raster_seg(
    const float4* __restrict__ recs, unsigned long long* __restrict__ packed,
    int F) {
  const int tx = threadIdx.x, ty = threadIdx.y;
  const int n = blockIdx.z / SEG_FLAT, s = blockIdx.z % SEG_FLAT;
  const int col = blockIdx.x * TSX + tx, row = blockIdx.y * TSY + ty;
  const float cx = (float)col, cy = (float)row;
  const float tX0 = (float)(blockIdx.x * TSX), tX1 = tX0 + (float)(TSX - 1);
  const float tY0 = (float)(blockIdx.y * TSY), tY1 = tY0 + (float)(TSY - 1);
  const float4* rb = recs + (size_t)n * F * 4;
  unsigned long long best = INIT_PACK;
  for (int f = s; f < F; f += SEG_FLAT) {
    float4 bb = rb[f * 4 + 3];
    if (bb.x > tX1 || bb.z < tX0 || bb.y > tY1 || bb.w < tY0) continue;
    float4 A = rb[f * 4 + 0];
    float4 B = rb[f * 4 + 1];
    float4 Z = rb[f * 4 + 2];
    test_face(A, B, Z, f, cx, cy, best);
  }
  if (best != INIT_PACK)
    atomicMin(&packed[(size_t)n * (HPIX * WPIX) + row * WPIX + col], best);
}

// Epilogue: interpolate colors for the winning face, apply any-positive mask,
// write NCHW. Recomputes weights via make_rec -> bit-identical values.
__device__ __forceinline__ void emit_pixel(float* __restrict__ out,
    const float* __restrict__ vb, const float* __restrict__ colors,
    const int* __restrict__ faces, int n, int V, int C, int bestf,
    float cx, float cy, int row, int col) {
#pragma clang fp contract(off)
  float cv[8];
#pragma unroll
  for (int ch = 0; ch < 8; ++ch) cv[ch] = 0.0f;
  if (bestf >= 0) {
    int i0 = faces[bestf * 3 + 0], i1 = faces[bestf * 3 + 1], i2 = faces[bestf * 3 + 2];
    FaceRec r = make_rec(vb, faces, bestf);
    float bx = cx - r.x2, by = cy - r.y2;
    float w0 = (r.a0 * bx + r.b0 * by) * r.inv;
    float w1 = (r.a1 * bx + r.b1 * by) * r.inv;
    float w2 = 1.0f - w0 - w1;
    const float* c0 = colors + ((size_t)n * V + i0) * C;
    const float* c1 = colors + ((size_t)n * V + i1) * C;
    const float* c2 = colors + ((size_t)n * V + i2) * C;
    for (int ch = 0; ch < C && ch < 8; ++ch)
      cv[ch] = (w0 * c0[ch] + w1 * c1[ch]) + w2 * c2[ch];
  }
  bool anyp = false;
  for (int ch = 0; ch < C && ch < 8; ++ch) anyp = anyp || (cv[ch] > 0.0f);
  float m = anyp ? 1.0f : 0.0f;
  size_t base = (size_t)n * C * HPIX * WPIX + (size_t)row * WPIX + col;
  for (int ch = 0; ch < C && ch < 8; ++ch)
    out[base + (size_t)ch * HPIX * WPIX] = cv[ch] * m;
}

__global__ __launch_bounds__(256) void resolve_kernel(
    const unsigned long long* __restrict__ packed,
    const float* __restrict__ verts, const float* __restrict__ colors,
    const int* __restrict__ faces, float* __restrict__ out,
    int V, int F, int C, int NIMG) {
  int i = blockIdx.x * blockDim.x + threadIdx.x;
  int total = NIMG * HPIX * WPIX;
  if (i >= total) return;
  int n = i / (HPIX * WPIX);
  int pix = i - n * (HPIX * WPIX);
  int row = pix >> 8, col = pix & 255;
  unsigned long long p = packed[i];
  int bestf = (p == INIT_PACK) ? -1 : (int)(unsigned int)(p & 0xFFFFFFFFull);
  emit_pixel(out, verts + (size_t)n * V * 3, colors, faces, n, V, C, bestf,
             (float)col, (float)row, row, col);
}

// ---- small-ws fallbacks (kept from round 1) ----
__global__ __launch_bounds__(256) void raster_g(const float4* __restrict__ recs,
    const float* __restrict__ verts, const float* __restrict__ colors,
    const int* __restrict__ faces, float* __restrict__ out, int V, int F, int C) {
#pragma clang fp contract(off)
  const int n = blockIdx.z;
  const int tx = threadIdx.x, ty = threadIdx.y;
  const int col = blockIdx.x * TSX + tx;
  const int row = blockIdx.y * TSY + ty;
  const float cx = (float)col, cy = (float)row;
  const float tX0 = (float)(blockIdx.x * TSX), tX1 = tX0 + (float)(TSX - 1);
  const float tY0 = (float)(blockIdx.y * TSY), tY1 = tY0 + (float)(TSY - 1);
  const float4* rb = recs + (size_t)n * F * 4;
  float bestd = BIGF;
  int bestf = -1;
  for (int f = 0; f < F; ++f) {
    float4 bb = rb[f * 4 + 3];
    if (bb.x > tX1 || bb.z < tX0 || bb.y > tY1 || bb.w < tY0) continue;
    float4 A = rb[f * 4 + 0];
    float4 B = rb[f * 4 + 1];
    float4 Z = rb[f * 4 + 2];
    float bx = cx - A.x, by = cy - A.y;
    float w0 = (A.z * bx + A.w * by) * B.z;
    float w1 = (B.x * bx + B.y * by) * B.z;
    float w2 = 1.0f - w0 - w1;
    float depth = (w0 * B.w + w1 * Z.x) + w2 * Z.y;
    bool ok = (w0 >= 0.0f) && (w1 >= 0.0f) && (w2 >= 0.0f) && (depth > 0.0f);
    float d = ok ? depth : BIGF;
    if (d < bestd) { bestd = d; bestf = f; }
  }
  emit_pixel(out, verts + (size_t)n * V * 3, colors, faces, n, V, C, bestf,
             cx, cy, row, col);
}

__global__ __launch_bounds__(256) void raster_l(const float* __restrict__ verts,
    const float* __restrict__ colors, const int* __restrict__ faces,
    float* __restrict__ out, int V, int F, int C) {
#pragma clang fp contract(off)
  __shared__ float4 sA[FCH], sB[FCH], sZ[FCH], sD[FCH];
  const int n = blockIdx.z;
  const int tx = threadIdx.x, ty = threadIdx.y;
  const int tid = ty * TSX + tx;
  const int col = blockIdx.x * TSX + tx;
  const int row = blockIdx.y * TSY + ty;
  const float cx = (float)col, cy = (float)row;
  const float tX0 = (float)(blockIdx.x * TSX), tX1 = tX0 + (float)(TSX - 1);
  const float tY0 = (float)(blockIdx.y * TSY), tY1 = tY0 + (float)(TSY - 1);
  const float* vb = verts + (size_t)n * V * 3;
  float bestd = BIGF;
  int bestf = -1;
  for (int base = 0; base < F; base += FCH) {
    int cnt = min(FCH, F - base);
    if (tid < cnt) {
      FaceRec r = make_rec(vb, faces, base + tid);
      sA[tid] = make_float4(r.x2, r.y2, r.a0, r.b0);
      sB[tid] = make_float4(r.a1, r.b1, r.inv, r.z0);
      sZ[tid] = make_float4(r.z1, r.z2, 0.0f, 0.0f);
      sD[tid] = make_float4(r.xmin, r.ymin, r.xmax, r.ymax);
    }
    __syncthreads();
    for (int j = 0; j < cnt; ++j) {
      float4 bb = sD[j];
      if (bb.x > tX1 || bb.z < tX0 || bb.y > tY1 || bb.w < tY0) continue;
      float4 A = sA[j];
      float4 B = sB[j];
      float4 Z = sZ[j];
      float bx = cx - A.x, by = cy - A.y;
      float w0 = (A.z * bx + A.w * by) * B.z;
      float w1 = (B.x * bx + B.y * by) * B.z;
      float w2 = 1.0f - w0 - w1;
      float depth = (w0 * B.w + w1 * Z.x) + w2 * Z.y;
      bool ok = (w0 >= 0.0f) && (w1 >= 0.0f) && (w2 >= 0.0f) && (depth > 0.0f);
      float d = ok ? depth : BIGF;
      if (d < bestd) { bestd = d; bestf = base + j; }
    }
    __syncthreads();
  }
  emit_pixel(out, vb, colors, faces, n, V, C, bestf, cx, cy, row, col);
}

extern "C" void kernel_launch(void* const* d_in, const int* in_sizes, int n_in,
                              void* d_out, int out_size, void* d_ws, size_t ws_size,
                              hipStream_t stream) {
  const float* verts = (const float*)d_in[0];
  const float* colors = (const float*)d_in[1];
  const int* faces = (const int*)d_in[2];
  float* out = (float*)d_out;
  long long s0 = in_sizes[0], s1 = in_sizes[1], s2 = in_sizes[2];
  int C = (int)((3LL * s1) / s0);
  if (C < 1) C = 1;
  int NC = out_size / (HPIX * WPIX);
  int N = NC / C;
  if (N < 1) N = 1;
  int V = (int)(s0 / (3LL * N));
  int F = (int)(s2 / 3);

  // ws layout: recs | packed | cursors | bins
  size_t offR = 0;
  size_t szR = (size_t)N * F * 4 * sizeof(float4);
  size_t offP = (offR + szR + 255) & ~(size_t)255;
  size_t szP = (size_t)N * HPIX * WPIX * sizeof(unsigned long long);
  size_t offC = (offP + szP + 255) & ~(size_t)255;
  size_t szC = (size_t)N * NTILE * sizeof(unsigned int);
  size_t offB = (offC + szC + 255) & ~(size_t)255;
  size_t szB = (size_t)N * NTILE * (size_t)F * sizeof(unsigned int);

  dim3 block(TSX, TSY);
  char* ws = (char*)d_ws;
  int total = N * F;
  int npix = N * HPIX * WPIX;

  if (d_ws != nullptr && ws_size >= offB + szB) {
    float4* recs = (float4*)(ws + offR);
    unsigned long long* packed = (unsigned long long*)(ws + offP);
    unsigned int* cursors = (unsigned int*)(ws + offC);
    unsigned int* bins = (unsigned int*)(ws + offB);
    init_kernel<<<(npix + 255) / 256, 256, 0, stream>>>(packed, cursors, npix,
                                                        N * NTILE);
    prep_kernel<<<(total + 255) / 256, 256, 0, stream>>>(verts, faces, recs, V, F, N);
    fill_kernel<<<(total + 255) / 256, 256, 0, stream>>>(recs, cursors, bins, F, N);
    raster_binned<<<dim3(16, 16, N * SEG_BIN), block, 0, stream>>>(recs, bins,
                                                                   cursors, packed, F);
    resolve_kernel<<<(npix + 255) / 256, 256, 0, stream>>>(packed, verts, colors,
                                                           faces, out, V, F, C, N);
  } else if (d_ws != nullptr && ws_size >= offC) {
    float4* recs = (float4*)(ws + offR);
    unsigned long long* packed = (unsigned long long*)(ws + offP);
    init_kernel<<<(npix + 255) / 256, 256, 0, stream>>>(packed, (unsigned int*)0,
                                                        npix, 0);
    prep_kernel<<<(total + 255) / 256, 256, 0, stream>>>(verts, faces, recs, V, F, N);
    raster_seg<<<dim3(16, 16, N * SEG_FLAT), block, 0, stream>>>(recs, packed, F);
    resolve_kernel<<<(npix + 255) / 256, 256, 0, stream>>>(packed, verts, colors,
                                                           faces, out, V, F, C, N);
  } else if (d_ws != nullptr && ws_size >= szR) {
    float4* recs = (float4*)(ws + offR);
    prep_kernel<<<(total + 255) / 256, 256, 0, stream>>>(verts, faces, recs, V, F, N);
    raster_g<<<dim3(16, 16, N), block, 0, stream>>>(recs, verts, colors, faces,
                                                    out, V, F, C);
  } else {
    raster_l<<<dim3(16, 16, N), block, 0, stream>>>(verts, colors, faces, out,
                                                    V, F, C);
  }
}

// Round 3
// 397.488 us; speedup vs baseline: 8.7948x; 3.9782x over previous
//
#include <hip/hip_runtime.h>

#define HPIX 256
#define WPIX 256
#define TSX 16
#define TSY 16
#define NTILE 256            // 16x16 tiles of 16x16 px
#define FCH 256
#define SEG_BIN 8            // segments per tile bin (binned path)
#define SEG_FLAT 16          // segments over all faces (fallback path)
#define BIGF 1000000000.0f
#define EPSF 1e-8f
#define MARGIN 0.125f
#define HP_SLOP 0.0625f      // >= 4x the FP eval error bound (~0.015 w-units)
#define INIT_PACK 0xFFFFFFFFFFFFFFFFull

struct FaceRec {
  float x2, y2, a0, b0, a1, b1, inv, z0, z1, z2;
  float xmin, ymin, xmax, ymax;
};

// Compute the per-face record with EXACTLY the reference's op order (no FMA).
__device__ __forceinline__ FaceRec make_rec(const float* __restrict__ vb,
                                            const int* __restrict__ faces, int f) {
#pragma clang fp contract(off)
  FaceRec r;
  int i0 = faces[f * 3 + 0], i1 = faces[f * 3 + 1], i2 = faces[f * 3 + 2];
  float x0 = vb[i0 * 3 + 0], y0 = vb[i0 * 3 + 1], z0 = vb[i0 * 3 + 2];
  float x1 = vb[i1 * 3 + 0], y1 = vb[i1 * 3 + 1], z1 = vb[i1 * 3 + 2];
  float x2 = vb[i2 * 3 + 0], y2 = vb[i2 * 3 + 1], z2 = vb[i2 * 3 + 2];
  float px0 = x0 / z0, py0 = y0 / z0;
  float px1 = x1 / z1, py1 = y1 / z1;
  float px2 = x2 / z2, py2 = y2 / z2;
  float a0 = py1 - py2, b0 = px2 - px1;   // (y1-y2), (x2-x1)
  float a1 = py2 - py0, b1 = px0 - px2;   // (y2-y0), (x0-x2)
  float dy02 = py0 - py2;
  float denom = a0 * b1 + b0 * dy02;      // (y1-y2)*(x0-x2) + (x2-x1)*(y0-y2)
  bool nz = fabsf(denom) > EPSF;
  bool valid = nz && (z0 > 0.0f) && (z1 > 0.0f) && (z2 > 0.0f);
  r.x2 = px2; r.y2 = py2; r.a0 = a0; r.b0 = b0; r.a1 = a1; r.b1 = b1;
  r.inv = valid ? 1.0f / denom : 0.0f;
  r.z0 = z0; r.z1 = z1;
  r.z2 = valid ? z2 : -1.0f;              // invalid -> depth<0 -> fails depth>0
  if (valid) {
    r.xmin = fminf(px0, fminf(px1, px2)) - MARGIN;
    r.xmax = fmaxf(px0, fmaxf(px1, px2)) + MARGIN;
    r.ymin = fminf(py0, fminf(py1, py2)) - MARGIN;
    r.ymax = fmaxf(py0, fmaxf(py1, py2)) + MARGIN;
  } else {
    r.xmin = 2.0f * BIGF; r.xmax = -2.0f * BIGF;
    r.ymin = 2.0f * BIGF; r.ymax = -2.0f * BIGF;
  }
  return r;
}

__global__ void prep_kernel(const float* __restrict__ verts,
                            const int* __restrict__ faces,
                            float4* __restrict__ recs, int V, int F, int NIMG) {
  int idx = blockIdx.x * blockDim.x + threadIdx.x;
  int total = NIMG * F;
  if (idx >= total) return;
  int n = idx / F, f = idx - n * F;
  FaceRec r = make_rec(verts + (size_t)n * V * 3, faces, f);
  float4* o = recs + (size_t)idx * 4;
  o[0] = make_float4(r.x2, r.y2, r.a0, r.b0);
  o[1] = make_float4(r.a1, r.b1, r.inv, r.z0);
  o[2] = make_float4(r.z1, r.z2, 0.0f, 0.0f);
  o[3] = make_float4(r.xmin, r.ymin, r.xmax, r.ymax);
}

__global__ void init_kernel(unsigned long long* __restrict__ packed, int npix) {
  int i = blockIdx.x * blockDim.x + threadIdx.x;
  if (i < npix) packed[i] = INIT_PACK;
}

// One block per (tile, image): threads stride faces, wave-compact survivors
// into the tile's bin with coalesced writes. Bin order is irrelevant: the
// packed (depth, face-idx) u64 min is order-independent.
__global__ __launch_bounds__(256) void bin_kernel(
    const float4* __restrict__ recs, unsigned int* __restrict__ cursors,
    unsigned int* __restrict__ bins, int F) {
#pragma clang fp contract(off)
  const int t = blockIdx.x;            // tile id
  const int n = blockIdx.y;            // image
  const int tlx = t & 15, tly = t >> 4;
  const float X0 = (float)(tlx * TSX), X1 = X0 + (float)(TSX - 1);
  const float Y0 = (float)(tly * TSY), Y1 = Y0 + (float)(TSY - 1);
  __shared__ unsigned int s_cur;
  if (threadIdx.x == 0) s_cur = 0u;
  __syncthreads();
  const float4* rb = recs + (size_t)n * F * 4;
  unsigned int* bin = bins + ((size_t)(n * NTILE + t)) * F;
  const int lane = threadIdx.x & 63;
  for (int base = 0; base < F; base += 256) {
    int f = base + (int)threadIdx.x;
    bool keep = false;
    if (f < F) {
      float4 D = rb[f * 4 + 3];
      keep = (D.x <= X1) && (D.z >= X0) && (D.y <= Y1) && (D.w >= Y0);
      if (keep) {
        float4 A = rb[f * 4 + 0];
        float4 B = rb[f * 4 + 1];
        float inv = B.z;
        if (fabsf(inv) <= 1.0f) {
          float m0 = -3.0e38f, m1 = -3.0e38f, m2 = -3.0e38f;
#pragma unroll
          for (int c = 0; c < 4; ++c) {
            float ccx = (c & 1) ? X1 : X0;
            float ccy = (c & 2) ? Y1 : Y0;
            float bx = ccx - A.x, by = ccy - A.y;
            float w0 = (A.z * bx + A.w * by) * inv;
            float w1 = (B.x * bx + B.y * by) * inv;
            float w2 = 1.0f - w0 - w1;
            m0 = fmaxf(m0, w0); m1 = fmaxf(m1, w1); m2 = fmaxf(m2, w2);
          }
          keep = (m0 >= -HP_SLOP) && (m1 >= -HP_SLOP) && (m2 >= -HP_SLOP);
        }
      }
    }
    unsigned long long m = __ballot(keep);
    int cntw = __popcll(m);
    unsigned int wbase = 0u;
    if (lane == 0 && cntw > 0) wbase = atomicAdd(&s_cur, (unsigned int)cntw);
    wbase = __shfl(wbase, 0);
    if (keep) {
      int off = __popcll(m & ((1ull << lane) - 1ull));
      bin[wbase + (unsigned int)off] = (unsigned int)f;
    }
  }
  __syncthreads();
  if (threadIdx.x == 0) cursors[n * NTILE + t] = s_cur;
}

// Exact per-pixel test, identical FP ops to the reference. Packed min gives
// min-depth with lowest-face-index tie-break (order-independent).
__device__ __forceinline__ void test_face(float4 A, float4 B, float4 Z, int f,
                                          float cx, float cy,
                                          unsigned long long& best) {
#pragma clang fp contract(off)
  float bx = cx - A.x, by = cy - A.y;
  float w0 = (A.z * bx + A.w * by) * B.z;
  float w1 = (B.x * bx + B.y * by) * B.z;
  float w2 = 1.0f - w0 - w1;
  float depth = (w0 * B.w + w1 * Z.x) + w2 * Z.y;
  bool ok = (w0 >= 0.0f) && (w1 >= 0.0f) && (w2 >= 0.0f) && (depth > 0.0f);
  if (ok) {
    unsigned long long p =
        ((unsigned long long)__float_as_uint(depth) << 32) | (unsigned int)f;
    best = p < best ? p : best;
  }
}

__global__ __launch_bounds__(256) void raster_binned(
    const float4* __restrict__ recs, const unsigned int* __restrict__ bins,
    const unsigned int* __restrict__ cursors,
    unsigned long long* __restrict__ packed, int F) {
  const int tx = threadIdx.x, ty = threadIdx.y;
  const int tileX = blockIdx.x, tileY = blockIdx.y;
  const int n = blockIdx.z / SEG_BIN, s = blockIdx.z % SEG_BIN;
  const int t = tileY * 16 + tileX;
  const int col = tileX * TSX + tx, row = tileY * TSY + ty;
  const float cx = (float)col, cy = (float)row;
  const float4* rb = recs + (size_t)n * F * 4;
  const unsigned int* bin = bins + ((size_t)(n * NTILE + t)) * F;
  const int cnt = (int)cursors[n * NTILE + t];
  unsigned long long best = INIT_PACK;
#pragma unroll 4
  for (int i = s; i < cnt; i += SEG_BIN) {
    int f = (int)bin[i];
    float4 A = rb[f * 4 + 0];
    float4 B = rb[f * 4 + 1];
    float4 Z = rb[f * 4 + 2];
    test_face(A, B, Z, f, cx, cy, best);
  }
  if (best != INIT_PACK)
    atomicMin(&packed[(size_t)n * (HPIX * WPIX) + row * WPIX + col], best);
}

// Fallback: no bins, segments over all faces with bbox reject.
__global__ __launch_bounds__(256) void raster_seg(
    const float4* __restrict__ recs, unsigned long long* __restrict__ packed,
    int F) {
  const int tx = threadIdx.x, ty = threadIdx.y;
  const int n = blockIdx.z / SEG_FLAT, s = blockIdx.z % SEG_FLAT;
  const int col = blockIdx.x * TSX + tx, row = blockIdx.y * TSY + ty;
  const float cx = (float)col, cy = (float)row;
  const float tX0 = (float)(blockIdx.x * TSX), tX1 = tX0 + (float)(TSX - 1);
  const float tY0 = (float)(blockIdx.y * TSY), tY1 = tY0 + (float)(TSY - 1);
  const float4* rb = recs + (size_t)n * F * 4;
  unsigned long long best = INIT_PACK;
  for (int f = s; f < F; f += SEG_FLAT) {
    float4 bb = rb[f * 4 + 3];
    if (bb.x > tX1 || bb.z < tX0 || bb.y > tY1 || bb.w < tY0) continue;
    float4 A = rb[f * 4 + 0];
    float4 B = rb[f * 4 + 1];
    float4 Z = rb[f * 4 + 2];
    test_face(A, B, Z, f, cx, cy, best);
  }
  if (best != INIT_PACK)
    atomicMin(&packed[(size_t)n * (HPIX * WPIX) + row * WPIX + col], best);
}

// Epilogue: interpolate colors for the winning face, apply any-positive mask,
// write NCHW. Recomputes weights via make_rec -> bit-identical values.
__device__ __forceinline__ void emit_pixel(float* __restrict__ out,
    const float* __restrict__ vb, const float* __restrict__ colors,
    const int* __restrict__ faces, int n, int V, int C, int bestf,
    float cx, float cy, int row, int col) {
#pragma clang fp contract(off)
  float cv[8];
#pragma unroll
  for (int ch = 0; ch < 8; ++ch) cv[ch] = 0.0f;
  if (bestf >= 0) {
    int i0 = faces[bestf * 3 + 0], i1 = faces[bestf * 3 + 1], i2 = faces[bestf * 3 + 2];
    FaceRec r = make_rec(vb, faces, bestf);
    float bx = cx - r.x2, by = cy - r.y2;
    float w0 = (r.a0 * bx + r.b0 * by) * r.inv;
    float w1 = (r.a1 * bx + r.b1 * by) * r.inv;
    float w2 = 1.0f - w0 - w1;
    const float* c0 = colors + ((size_t)n * V + i0) * C;
    const float* c1 = colors + ((size_t)n * V + i1) * C;
    const float* c2 = colors + ((size_t)n * V + i2) * C;
    for (int ch = 0; ch < C && ch < 8; ++ch)
      cv[ch] = (w0 * c0[ch] + w1 * c1[ch]) + w2 * c2[ch];
  }
  bool anyp = false;
  for (int ch = 0; ch < C && ch < 8; ++ch) anyp = anyp || (cv[ch] > 0.0f);
  float m = anyp ? 1.0f : 0.0f;
  size_t base = (size_t)n * C * HPIX * WPIX + (size_t)row * WPIX + col;
  for (int ch = 0; ch < C && ch < 8; ++ch)
    out[base + (size_t)ch * HPIX * WPIX] = cv[ch] * m;
}

__global__ __launch_bounds__(256) void resolve_kernel(
    const unsigned long long* __restrict__ packed,
    const float* __restrict__ verts, const float* __restrict__ colors,
    const int* __restrict__ faces, float* __restrict__ out,
    int V, int F, int C, int NIMG) {
  int i = blockIdx.x * blockDim.x + threadIdx.x;
  int total = NIMG * HPIX * WPIX;
  if (i >= total) return;
  int n = i / (HPIX * WPIX);
  int pix = i - n * (HPIX * WPIX);
  int row = pix >> 8, col = pix & 255;
  unsigned long long p = packed[i];
  int bestf = (p == INIT_PACK) ? -1 : (int)(unsigned int)(p & 0xFFFFFFFFull);
  emit_pixel(out, verts + (size_t)n * V * 3, colors, faces, n, V, C, bestf,
             (float)col, (float)row, row, col);
}

// ---- small-ws fallbacks ----
__global__ __launch_bounds__(256) void raster_g(const float4* __restrict__ recs,
    const float* __restrict__ verts, const float* __restrict__ colors,
    const int* __restrict__ faces, float* __restrict__ out, int V, int F, int C) {
#pragma clang fp contract(off)
  const int n = blockIdx.z;
  const int tx = threadIdx.x, ty = threadIdx.y;
  const int col = blockIdx.x * TSX + tx;
  const int row = blockIdx.y * TSY + ty;
  const float cx = (float)col, cy = (float)row;
  const float tX0 = (float)(blockIdx.x * TSX), tX1 = tX0 + (float)(TSX - 1);
  const float tY0 = (float)(blockIdx.y * TSY), tY1 = tY0 + (float)(TSY - 1);
  const float4* rb = recs + (size_t)n * F * 4;
  float bestd = BIGF;
  int bestf = -1;
  for (int f = 0; f < F; ++f) {
    float4 bb = rb[f * 4 + 3];
    if (bb.x > tX1 || bb.z < tX0 || bb.y > tY1 || bb.w < tY0) continue;
    float4 A = rb[f * 4 + 0];
    float4 B = rb[f * 4 + 1];
    float4 Z = rb[f * 4 + 2];
    float bx = cx - A.x, by = cy - A.y;
    float w0 = (A.z * bx + A.w * by) * B.z;
    float w1 = (B.x * bx + B.y * by) * B.z;
    float w2 = 1.0f - w0 - w1;
    float depth = (w0 * B.w + w1 * Z.x) + w2 * Z.y;
    bool ok = (w0 >= 0.0f) && (w1 >= 0.0f) && (w2 >= 0.0f) && (depth > 0.0f);
    float d = ok ? depth : BIGF;
    if (d < bestd) { bestd = d; bestf = f; }
  }
  emit_pixel(out, verts + (size_t)n * V * 3, colors, faces, n, V, C, bestf,
             cx, cy, row, col);
}

__global__ __launch_bounds__(256) void raster_l(const float* __restrict__ verts,
    const float* __restrict__ colors, const int* __restrict__ faces,
    float* __restrict__ out, int V, int F, int C) {
#pragma clang fp contract(off)
  __shared__ float4 sA[FCH], sB[FCH], sZ[FCH], sD[FCH];
  const int n = blockIdx.z;
  const int tx = threadIdx.x, ty = threadIdx.y;
  const int tid = ty * TSX + tx;
  const int col = blockIdx.x * TSX + tx;
  const int row = blockIdx.y * TSY + ty;
  const float cx = (float)col, cy = (float)row;
  const float tX0 = (float)(blockIdx.x * TSX), tX1 = tX0 + (float)(TSX - 1);
  const float tY0 = (float)(blockIdx.y * TSY), tY1 = tY0 + (float)(TSY - 1);
  const float* vb = verts + (size_t)n * V * 3;
  float bestd = BIGF;
  int bestf = -1;
  for (int base = 0; base < F; base += FCH) {
    int cnt = min(FCH, F - base);
    if (tid < cnt) {
      FaceRec r = make_rec(vb, faces, base + tid);
      sA[tid] = make_float4(r.x2, r.y2, r.a0, r.b0);
      sB[tid] = make_float4(r.a1, r.b1, r.inv, r.z0);
      sZ[tid] = make_float4(r.z1, r.z2, 0.0f, 0.0f);
      sD[tid] = make_float4(r.xmin, r.ymin, r.xmax, r.ymax);
    }
    __syncthreads();
    for (int j = 0; j < cnt; ++j) {
      float4 bb = sD[j];
      if (bb.x > tX1 || bb.z < tX0 || bb.y > tY1 || bb.w < tY0) continue;
      float4 A = sA[j];
      float4 B = sB[j];
      float4 Z = sZ[j];
      float bx = cx - A.x, by = cy - A.y;
      float w0 = (A.z * bx + A.w * by) * B.z;
      float w1 = (B.x * bx + B.y * by) * B.z;
      float w2 = 1.0f - w0 - w1;
      float depth = (w0 * B.w + w1 * Z.x) + w2 * Z.y;
      bool ok = (w0 >= 0.0f) && (w1 >= 0.0f) && (w2 >= 0.0f) && (depth > 0.0f);
      float d = ok ? depth : BIGF;
      if (d < bestd) { bestd = d; bestf = base + j; }
    }
    __syncthreads();
  }
  emit_pixel(out, vb, colors, faces, n, V, C, bestf, cx, cy, row, col);
}

extern "C" void kernel_launch(void* const* d_in, const int* in_sizes, int n_in,
                              void* d_out, int out_size, void* d_ws, size_t ws_size,
                              hipStream_t stream) {
  const float* verts = (const float*)d_in[0];
  const float* colors = (const float*)d_in[1];
  const int* faces = (const int*)d_in[2];
  float* out = (float*)d_out;
  long long s0 = in_sizes[0], s1 = in_sizes[1], s2 = in_sizes[2];
  int C = (int)((3LL * s1) / s0);
  if (C < 1) C = 1;
  int NC = out_size / (HPIX * WPIX);
  int N = NC / C;
  if (N < 1) N = 1;
  int V = (int)(s0 / (3LL * N));
  int F = (int)(s2 / 3);

  // ws layout: recs | packed | cursors | bins
  size_t offR = 0;
  size_t szR = (size_t)N * F * 4 * sizeof(float4);
  size_t offP = (offR + szR + 255) & ~(size_t)255;
  size_t szP = (size_t)N * HPIX * WPIX * sizeof(unsigned long long);
  size_t offC = (offP + szP + 255) & ~(size_t)255;
  size_t szC = (size_t)N * NTILE * sizeof(unsigned int);
  size_t offB = (offC + szC + 255) & ~(size_t)255;
  size_t szB = (size_t)N * NTILE * (size_t)F * sizeof(unsigned int);

  dim3 block(TSX, TSY);
  char* ws = (char*)d_ws;
  int total = N * F;
  int npix = N * HPIX * WPIX;

  if (d_ws != nullptr && ws_size >= offB + szB) {
    float4* recs = (float4*)(ws + offR);
    unsigned long long* packed = (unsigned long long*)(ws + offP);
    unsigned int* cursors = (unsigned int*)(ws + offC);
    unsigned int* bins = (unsigned int*)(ws + offB);
    init_kernel<<<(npix + 255) / 256, 256, 0, stream>>>(packed, npix);
    prep_kernel<<<(total + 255) / 256, 256, 0, stream>>>(verts, faces, recs, V, F, N);
    bin_kernel<<<dim3(NTILE, N), 256, 0, stream>>>(recs, cursors, bins, F);
    raster_binned<<<dim3(16, 16, N * SEG_BIN), block, 0, stream>>>(recs, bins,
                                                                   cursors, packed, F);
    resolve_kernel<<<(npix + 255) / 256, 256, 0, stream>>>(packed, verts, colors,
                                                           faces, out, V, F, C, N);
  } else if (d_ws != nullptr && ws_size >= offC) {
    float4* recs = (float4*)(ws + offR);
    unsigned long long* packed = (unsigned long long*)(ws + offP);
    init_kernel<<<(npix + 255) / 256, 256, 0, stream>>>(packed, npix);
    prep_kernel<<<(total + 255) / 256, 256, 0, stream>>>(verts, faces, recs, V, F, N);
    raster_seg<<<dim3(16, 16, N * SEG_FLAT), block, 0, stream>>>(recs, packed, F);
    resolve_kernel<<<(npix + 255) / 256, 256, 0, stream>>>(packed, verts, colors,
                                                           faces, out, V, F, C, N);
  } else if (d_ws != nullptr && ws_size >= szR) {
    float4* recs = (float4*)(ws + offR);
    prep_kernel<<<(total + 255) / 256, 256, 0, stream>>>(verts, faces, recs, V, F, N);
    raster_g<<<dim3(16, 16, N), block, 0, stream>>>(recs, verts, colors, faces,
                                                    out, V, F, C);
  } else {
    raster_l<<<dim3(16, 16, N), block, 0, stream>>>(verts, colors, faces, out,
                                                    V, F, C);
  }
}

// Round 4
// 329.743 us; speedup vs baseline: 10.6016x; 1.2054x over previous
//
#include <hip/hip_runtime.h>

#define HPIX 256
#define WPIX 256
#define TSX 16
#define TSY 16
#define NTILE 256            // 16x16 tiles of 16x16 px
#define FCH 256
#define SEG_FLAT 16          // segments over all faces (fallback path)
#define NBUCK 4096           // minz counting-sort buckets over [1,2)
#define BIGF 1000000000.0f
#define EPSF 1e-8f
#define MARGIN 0.125f
#define HP_SLOP 0.0625f      // >= 4x the FP eval error bound (~0.015 w-units)
#define EPSZ 1e-4f           // early-exit slack >> depth/minz FP error (~2e-6)
#define INIT_PACK 0xFFFFFFFFFFFFFFFFull

struct FaceRec {
  float x2, y2, a0, b0, a1, b1, inv, z0, z1, z2;
  float xmin, ymin, xmax, ymax;
};

// Compute the per-face record with EXACTLY the reference's op order (no FMA).
__device__ __forceinline__ FaceRec make_rec(const float* __restrict__ vb,
                                            const int* __restrict__ faces, int f) {
#pragma clang fp contract(off)
  FaceRec r;
  int i0 = faces[f * 3 + 0], i1 = faces[f * 3 + 1], i2 = faces[f * 3 + 2];
  float x0 = vb[i0 * 3 + 0], y0 = vb[i0 * 3 + 1], z0 = vb[i0 * 3 + 2];
  float x1 = vb[i1 * 3 + 0], y1 = vb[i1 * 3 + 1], z1 = vb[i1 * 3 + 2];
  float x2 = vb[i2 * 3 + 0], y2 = vb[i2 * 3 + 1], z2 = vb[i2 * 3 + 2];
  float px0 = x0 / z0, py0 = y0 / z0;
  float px1 = x1 / z1, py1 = y1 / z1;
  float px2 = x2 / z2, py2 = y2 / z2;
  float a0 = py1 - py2, b0 = px2 - px1;   // (y1-y2), (x2-x1)
  float a1 = py2 - py0, b1 = px0 - px2;   // (y2-y0), (x0-x2)
  float dy02 = py0 - py2;
  float denom = a0 * b1 + b0 * dy02;      // (y1-y2)*(x0-x2) + (x2-x1)*(y0-y2)
  bool nz = fabsf(denom) > EPSF;
  bool valid = nz && (z0 > 0.0f) && (z1 > 0.0f) && (z2 > 0.0f);
  r.x2 = px2; r.y2 = py2; r.a0 = a0; r.b0 = b0; r.a1 = a1; r.b1 = b1;
  r.inv = valid ? 1.0f / denom : 0.0f;
  r.z0 = z0; r.z1 = z1;
  r.z2 = valid ? z2 : -1.0f;              // invalid -> depth<0 -> fails depth>0
  if (valid) {
    r.xmin = fminf(px0, fminf(px1, px2)) - MARGIN;
    r.xmax = fmaxf(px0, fmaxf(px1, px2)) + MARGIN;
    r.ymin = fminf(py0, fminf(py1, py2)) - MARGIN;
    r.ymax = fmaxf(py0, fmaxf(py1, py2)) + MARGIN;
  } else {
    r.xmin = 2.0f * BIGF; r.xmax = -2.0f * BIGF;
    r.ymin = 2.0f * BIGF; r.ymax = -2.0f * BIGF;
  }
  return r;
}

// Same arithmetic as make_rec for the validity flag + minz (must match exactly).
__device__ __forceinline__ void classify(const float* __restrict__ vb,
                                         const int* __restrict__ faces, int f,
                                         bool& valid, float& minz) {
#pragma clang fp contract(off)
  int i0 = faces[f * 3 + 0], i1 = faces[f * 3 + 1], i2 = faces[f * 3 + 2];
  float x0 = vb[i0 * 3 + 0], y0 = vb[i0 * 3 + 1], z0 = vb[i0 * 3 + 2];
  float x1 = vb[i1 * 3 + 0], y1 = vb[i1 * 3 + 1], z1 = vb[i1 * 3 + 2];
  float x2 = vb[i2 * 3 + 0], y2 = vb[i2 * 3 + 1], z2 = vb[i2 * 3 + 2];
  float px0 = x0 / z0, py0 = y0 / z0;
  float px1 = x1 / z1, py1 = y1 / z1;
  float px2 = x2 / z2, py2 = y2 / z2;
  float a0 = py1 - py2, b0 = px2 - px1;
  float b1 = px0 - px2;
  float dy02 = py0 - py2;
  float denom = a0 * b1 + b0 * dy02;
  bool nz = fabsf(denom) > EPSF;
  valid = nz && (z0 > 0.0f) && (z1 > 0.0f) && (z2 > 0.0f);
  minz = fminf(z0, fminf(z1, z2));
}

// ---------- sorted path ----------
__global__ void zero_hist_kernel(unsigned int* __restrict__ hist, int n) {
  int i = blockIdx.x * blockDim.x + threadIdx.x;
  if (i < n) hist[i] = 0u;
}

__global__ void key_hist_kernel(const float* __restrict__ verts,
                                const int* __restrict__ faces,
                                unsigned int* __restrict__ keys,
                                unsigned int* __restrict__ hist,
                                int V, int F, int NIMG) {
  int idx = blockIdx.x * blockDim.x + threadIdx.x;
  if (idx >= NIMG * F) return;
  int n = idx / F, f = idx - n * F;
  bool valid; float minz;
  classify(verts + (size_t)n * V * 3, faces, f, valid, minz);
  int b;
  if (!valid) b = NBUCK - 1;
  else {
    float t = (minz - 1.0f) * (float)NBUCK;
    b = (int)floorf(t);
    b = b < 0 ? 0 : (b > NBUCK - 1 ? NBUCK - 1 : b);
  }
  keys[idx] = (unsigned int)b;
  atomicAdd(&hist[n * NBUCK + b], 1u);
}

__global__ __launch_bounds__(1024) void scan_kernel(unsigned int* __restrict__ hist) {
  __shared__ unsigned int s[1024];
  unsigned int* h = hist + (size_t)blockIdx.x * NBUCK;
  int t = threadIdx.x;
  unsigned int v0 = h[4 * t], v1 = h[4 * t + 1], v2 = h[4 * t + 2], v3 = h[4 * t + 3];
  unsigned int sum = v0 + v1 + v2 + v3;
  s[t] = sum;
  __syncthreads();
  for (int off = 1; off < 1024; off <<= 1) {
    unsigned int x = (t >= off) ? s[t - off] : 0u;
    __syncthreads();
    s[t] += x;
    __syncthreads();
  }
  unsigned int excl = s[t] - sum;
  h[4 * t] = excl;
  h[4 * t + 1] = excl + v0;
  h[4 * t + 2] = excl + v0 + v1;
  h[4 * t + 3] = excl + v0 + v1 + v2;
}

// Scatter recs into minz-bucket-sorted order. o[2].z = key_lo (round-down
// bucket bound, <= true minz); o[2].w = original face id (bit transport).
__global__ void scatter_kernel(const float* __restrict__ verts,
                               const int* __restrict__ faces,
                               const unsigned int* __restrict__ keys,
                               unsigned int* __restrict__ hist,
                               float4* __restrict__ srecs,
                               int V, int F, int NIMG) {
  int idx = blockIdx.x * blockDim.x + threadIdx.x;
  if (idx >= NIMG * F) return;
  int n = idx / F, f = idx - n * F;
  const float* vb = verts + (size_t)n * V * 3;
  FaceRec r = make_rec(vb, faces, f);
  bool valid; float minz;
  classify(vb, faces, f, valid, minz);
  unsigned int b = keys[idx];
  // bucket 0 uses a sentinel so minz<1 robustness can't cause early-exit bugs
  float key_lo = (b == 0u) ? -3.0e38f
               : fminf(1.0f + (float)b * (1.0f / (float)NBUCK),
                       valid ? minz : 3.0e38f);
  unsigned int pos = atomicAdd(&hist[n * NBUCK + b], 1u);
  float4* o = srecs + ((size_t)n * F + pos) * 4;
  o[0] = make_float4(r.x2, r.y2, r.a0, r.b0);
  o[1] = make_float4(r.a1, r.b1, r.inv, r.z0);
  o[2] = make_float4(r.z1, r.z2, key_lo, __int_as_float(f));
  o[3] = make_float4(r.xmin, r.ymin, r.xmax, r.ymax);
}

// Order-preserving binning: iterate sorted positions j in chunks of 256;
// block-ordered compaction keeps each bin ascending in j (=> ascending key_lo).
__global__ __launch_bounds__(256) void bin_kernel(
    const float4* __restrict__ srecs, unsigned int* __restrict__ cursors,
    unsigned int* __restrict__ bins, int F) {
#pragma clang fp contract(off)
  const int t = blockIdx.x, n = blockIdx.y;
  const int tlx = t & 15, tly = t >> 4;
  const float X0 = (float)(tlx * TSX), X1 = X0 + (float)(TSX - 1);
  const float Y0 = (float)(tly * TSY), Y1 = Y0 + (float)(TSY - 1);
  __shared__ unsigned int s_cnt[4];
  __shared__ unsigned int s_cur;
  const int tid = (int)threadIdx.x;
  const int lane = tid & 63, wid = tid >> 6;
  if (tid == 0) s_cur = 0u;
  __syncthreads();
  const float4* rb = srecs + (size_t)n * F * 4;
  unsigned int* bin = bins + ((size_t)(n * NTILE + t)) * F;
  for (int base = 0; base < F; base += 256) {
    int j = base + tid;
    bool keep = false;
    if (j < F) {
      float4 D = rb[j * 4 + 3];
      keep = (D.x <= X1) && (D.z >= X0) && (D.y <= Y1) && (D.w >= Y0);
      if (keep) {
        float4 A = rb[j * 4 + 0];
        float4 B = rb[j * 4 + 1];
        float inv = B.z;
        if (fabsf(inv) <= 1.0f) {
          float m0 = -3.0e38f, m1 = -3.0e38f, m2 = -3.0e38f;
#pragma unroll
          for (int c = 0; c < 4; ++c) {
            float ccx = (c & 1) ? X1 : X0;
            float ccy = (c & 2) ? Y1 : Y0;
            float bx = ccx - A.x, by = ccy - A.y;
            float w0 = (A.z * bx + A.w * by) * inv;
            float w1 = (B.x * bx + B.y * by) * inv;
            float w2 = 1.0f - w0 - w1;
            m0 = fmaxf(m0, w0); m1 = fmaxf(m1, w1); m2 = fmaxf(m2, w2);
          }
          keep = (m0 >= -HP_SLOP) && (m1 >= -HP_SLOP) && (m2 >= -HP_SLOP);
        }
      }
    }
    unsigned long long m = __ballot(keep);
    int cw = __popcll(m);
    if (lane == 0) s_cnt[wid] = (unsigned int)cw;
    __syncthreads();
    unsigned int woff = s_cur;
    for (int w = 0; w < wid; ++w) woff += s_cnt[w];
    unsigned int tot = s_cnt[0] + s_cnt[1] + s_cnt[2] + s_cnt[3];
    if (keep) {
      int off = __popcll(m & ((1ull << lane) - 1ull));
      bin[woff + (unsigned int)off] = (unsigned int)j;
    }
    __syncthreads();             // all reads of s_cur/s_cnt done
    if (tid == 0) s_cur += tot;
  }
  __syncthreads();
  if (tid == 0) cursors[n * NTILE + t] = s_cur;
}

// Epilogue: interpolate colors for the winning face, apply any-positive mask,
// write NCHW. Recomputes weights via make_rec -> bit-identical values.
__device__ __forceinline__ void emit_pixel(float* __restrict__ out,
    const float* __restrict__ vb, const float* __restrict__ colors,
    const int* __restrict__ faces, int n, int V, int C, int bestf,
    float cx, float cy, int row, int col) {
#pragma clang fp contract(off)
  float cv[8];
#pragma unroll
  for (int ch = 0; ch < 8; ++ch) cv[ch] = 0.0f;
  if (bestf >= 0) {
    int i0 = faces[bestf * 3 + 0], i1 = faces[bestf * 3 + 1], i2 = faces[bestf * 3 + 2];
    FaceRec r = make_rec(vb, faces, bestf);
    float bx = cx - r.x2, by = cy - r.y2;
    float w0 = (r.a0 * bx + r.b0 * by) * r.inv;
    float w1 = (r.a1 * bx + r.b1 * by) * r.inv;
    float w2 = 1.0f - w0 - w1;
    const float* c0 = colors + ((size_t)n * V + i0) * C;
    const float* c1 = colors + ((size_t)n * V + i1) * C;
    const float* c2 = colors + ((size_t)n * V + i2) * C;
    for (int ch = 0; ch < C && ch < 8; ++ch)
      cv[ch] = (w0 * c0[ch] + w1 * c1[ch]) + w2 * c2[ch];
  }
  bool anyp = false;
  for (int ch = 0; ch < C && ch < 8; ++ch) anyp = anyp || (cv[ch] > 0.0f);
  float m = anyp ? 1.0f : 0.0f;
  size_t base = (size_t)n * C * HPIX * WPIX + (size_t)row * WPIX + col;
  for (int ch = 0; ch < C && ch < 8; ++ch)
    out[base + (size_t)ch * HPIX * WPIX] = cv[ch] * m;
}

// One block per (tile,image); per-wave early exit on sorted minz; fused emit.
__global__ __launch_bounds__(256) void raster_sorted(
    const float4* __restrict__ srecs, const unsigned int* __restrict__ bins,
    const unsigned int* __restrict__ cursors, const float* __restrict__ verts,
    const float* __restrict__ colors, const int* __restrict__ faces,
    float* __restrict__ out, int V, int F, int C) {
#pragma clang fp contract(off)
  const int t = blockIdx.x, n = blockIdx.y;
  const int tlx = t & 15, tly = t >> 4;
  const int tx = (int)threadIdx.x & 15, ty = (int)threadIdx.x >> 4;
  const int col = tlx * TSX + tx, row = tly * TSY + ty;
  const float cx = (float)col, cy = (float)row;
  const float4* rb = srecs + (size_t)n * F * 4;
  const unsigned int* bin = bins + ((size_t)(n * NTILE + t)) * F;
  const int cnt = (int)cursors[n * NTILE + t];
  unsigned long long best = INIT_PACK;
  float d = BIGF;
  for (int i = 0; i < cnt; ++i) {
    int j = (int)bin[i];
    float4 Z = rb[j * 4 + 2];          // (z1, z2, key_lo, forig_bits)
    if (__all(Z.z > d + EPSZ)) break;  // all later faces have depth > d strictly
    float4 A = rb[j * 4 + 0];
    float4 B = rb[j * 4 + 1];
    float bx = cx - A.x, by = cy - A.y;
    float w0 = (A.z * bx + A.w * by) * B.z;
    float w1 = (B.x * bx + B.y * by) * B.z;
    float w2 = 1.0f - w0 - w1;
    float depth = (w0 * B.w + w1 * Z.x) + w2 * Z.y;
    bool ok = (w0 >= 0.0f) && (w1 >= 0.0f) && (w2 >= 0.0f) && (depth > 0.0f);
    if (ok) {
      unsigned int forig = (unsigned int)__float_as_int(Z.w);
      unsigned long long p =
          ((unsigned long long)__float_as_uint(depth) << 32) | forig;
      if (p < best) { best = p; d = depth; }
    }
  }
  int bestf = (best == INIT_PACK) ? -1 : (int)(unsigned int)(best & 0xFFFFFFFFull);
  emit_pixel(out, verts + (size_t)n * V * 3, colors, faces, n, V, C, bestf,
             cx, cy, row, col);
}

// ---------- fallbacks (smaller ws) ----------
__global__ void prep_kernel(const float* __restrict__ verts,
                            const int* __restrict__ faces,
                            float4* __restrict__ recs, int V, int F, int NIMG) {
  int idx = blockIdx.x * blockDim.x + threadIdx.x;
  int total = NIMG * F;
  if (idx >= total) return;
  int n = idx / F, f = idx - n * F;
  FaceRec r = make_rec(verts + (size_t)n * V * 3, faces, f);
  float4* o = recs + (size_t)idx * 4;
  o[0] = make_float4(r.x2, r.y2, r.a0, r.b0);
  o[1] = make_float4(r.a1, r.b1, r.inv, r.z0);
  o[2] = make_float4(r.z1, r.z2, 0.0f, 0.0f);
  o[3] = make_float4(r.xmin, r.ymin, r.xmax, r.ymax);
}

__global__ void init_kernel(unsigned long long* __restrict__ packed, int npix) {
  int i = blockIdx.x * blockDim.x + threadIdx.x;
  if (i < npix) packed[i] = INIT_PACK;
}

__device__ __forceinline__ void test_face(float4 A, float4 B, float4 Z, int f,
                                          float cx, float cy,
                                          unsigned long long& best) {
#pragma clang fp contract(off)
  float bx = cx - A.x, by = cy - A.y;
  float w0 = (A.z * bx + A.w * by) * B.z;
  float w1 = (B.x * bx + B.y * by) * B.z;
  float w2 = 1.0f - w0 - w1;
  float depth = (w0 * B.w + w1 * Z.x) + w2 * Z.y;
  bool ok = (w0 >= 0.0f) && (w1 >= 0.0f) && (w2 >= 0.0f) && (depth > 0.0f);
  if (ok) {
    unsigned long long p =
        ((unsigned long long)__float_as_uint(depth) << 32) | (unsigned int)f;
    best = p < best ? p : best;
  }
}

__global__ __launch_bounds__(256) void raster_seg(
    const float4* __restrict__ recs, unsigned long long* __restrict__ packed,
    int F) {
  const int tx = threadIdx.x, ty = threadIdx.y;
  const int n = blockIdx.z / SEG_FLAT, s = blockIdx.z % SEG_FLAT;
  const int col = blockIdx.x * TSX + tx, row = blockIdx.y * TSY + ty;
  const float cx = (float)col, cy = (float)row;
  const float tX0 = (float)(blockIdx.x * TSX), tX1 = tX0 + (float)(TSX - 1);
  const float tY0 = (float)(blockIdx.y * TSY), tY1 = tY0 + (float)(TSY - 1);
  const float4* rb = recs + (size_t)n * F * 4;
  unsigned long long best = INIT_PACK;
  for (int f = s; f < F; f += SEG_FLAT) {
    float4 bb = rb[f * 4 + 3];
    if (bb.x > tX1 || bb.z < tX0 || bb.y > tY1 || bb.w < tY0) continue;
    float4 A = rb[f * 4 + 0];
    float4 B = rb[f * 4 + 1];
    float4 Z = rb[f * 4 + 2];
    test_face(A, B, Z, f, cx, cy, best);
  }
  if (best != INIT_PACK)
    atomicMin(&packed[(size_t)n * (HPIX * WPIX) + row * WPIX + col], best);
}

__global__ __launch_bounds__(256) void resolve_kernel(
    const unsigned long long* __restrict__ packed,
    const float* __restrict__ verts, const float* __restrict__ colors,
    const int* __restrict__ faces, float* __restrict__ out,
    int V, int F, int C, int NIMG) {
  int i = blockIdx.x * blockDim.x + threadIdx.x;
  int total = NIMG * HPIX * WPIX;
  if (i >= total) return;
  int n = i / (HPIX * WPIX);
  int pix = i - n * (HPIX * WPIX);
  int row = pix >> 8, col = pix & 255;
  unsigned long long p = packed[i];
  int bestf = (p == INIT_PACK) ? -1 : (int)(unsigned int)(p & 0xFFFFFFFFull);
  emit_pixel(out, verts + (size_t)n * V * 3, colors, faces, n, V, C, bestf,
             (float)col, (float)row, row, col);
}

__global__ __launch_bounds__(256) void raster_l(const float* __restrict__ verts,
    const float* __restrict__ colors, const int* __restrict__ faces,
    float* __restrict__ out, int V, int F, int C) {
#pragma clang fp contract(off)
  __shared__ float4 sA[FCH], sB[FCH], sZ[FCH], sD[FCH];
  const int n = blockIdx.z;
  const int tx = threadIdx.x, ty = threadIdx.y;
  const int tid = ty * TSX + tx;
  const int col = blockIdx.x * TSX + tx;
  const int row = blockIdx.y * TSY + ty;
  const float cx = (float)col, cy = (float)row;
  const float tX0 = (float)(blockIdx.x * TSX), tX1 = tX0 + (float)(TSX - 1);
  const float tY0 = (float)(blockIdx.y * TSY), tY1 = tY0 + (float)(TSY - 1);
  const float* vb = verts + (size_t)n * V * 3;
  float bestd = BIGF;
  int bestf = -1;
  for (int base = 0; base < F; base += FCH) {
    int cnt = min(FCH, F - base);
    if (tid < cnt) {
      FaceRec r = make_rec(vb, faces, base + tid);
      sA[tid] = make_float4(r.x2, r.y2, r.a0, r.b0);
      sB[tid] = make_float4(r.a1, r.b1, r.inv, r.z0);
      sZ[tid] = make_float4(r.z1, r.z2, 0.0f, 0.0f);
      sD[tid] = make_float4(r.xmin, r.ymin, r.xmax, r.ymax);
    }
    __syncthreads();
    for (int j = 0; j < cnt; ++j) {
      float4 bb = sD[j];
      if (bb.x > tX1 || bb.z < tX0 || bb.y > tY1 || bb.w < tY0) continue;
      float4 A = sA[j];
      float4 B = sB[j];
      float4 Z = sZ[j];
      float bx = cx - A.x, by = cy - A.y;
      float w0 = (A.z * bx + A.w * by) * B.z;
      float w1 = (B.x * bx + B.y * by) * B.z;
      float w2 = 1.0f - w0 - w1;
      float depth = (w0 * B.w + w1 * Z.x) + w2 * Z.y;
      bool ok = (w0 >= 0.0f) && (w1 >= 0.0f) && (w2 >= 0.0f) && (depth > 0.0f);
      float d = ok ? depth : BIGF;
      if (d < bestd) { bestd = d; bestf = base + j; }
    }
    __syncthreads();
  }
  emit_pixel(out, vb, colors, faces, n, V, C, bestf, cx, cy, row, col);
}

extern "C" void kernel_launch(void* const* d_in, const int* in_sizes, int n_in,
                              void* d_out, int out_size, void* d_ws, size_t ws_size,
                              hipStream_t stream) {
  const float* verts = (const float*)d_in[0];
  const float* colors = (const float*)d_in[1];
  const int* faces = (const int*)d_in[2];
  float* out = (float*)d_out;
  long long s0 = in_sizes[0], s1 = in_sizes[1], s2 = in_sizes[2];
  int C = (int)((3LL * s1) / s0);
  if (C < 1) C = 1;
  int NC = out_size / (HPIX * WPIX);
  int N = NC / C;
  if (N < 1) N = 1;
  int V = (int)(s0 / (3LL * N));
  int F = (int)(s2 / 3);

  // sorted-path ws layout: srecs | keys | hist | cursors | bins
  size_t offS = 0;
  size_t szS = (size_t)N * F * 4 * sizeof(float4);
  size_t offK = (offS + szS + 255) & ~(size_t)255;
  size_t szK = (size_t)N * F * sizeof(unsigned int);
  size_t offH = (offK + szK + 255) & ~(size_t)255;
  size_t szH = (size_t)N * NBUCK * sizeof(unsigned int);
  size_t offC2 = (offH + szH + 255) & ~(size_t)255;
  size_t szC2 = (size_t)N * NTILE * sizeof(unsigned int);
  size_t offB2 = (offC2 + szC2 + 255) & ~(size_t)255;
  size_t szB2 = (size_t)N * NTILE * (size_t)F * sizeof(unsigned int);
  size_t need_sorted = offB2 + szB2;

  // fallback layout: recs | packed
  size_t szR = (size_t)N * F * 4 * sizeof(float4);
  size_t offP = (szR + 255) & ~(size_t)255;
  size_t szP = (size_t)N * HPIX * WPIX * sizeof(unsigned long long);

  dim3 block(TSX, TSY);
  char* ws = (char*)d_ws;
  int total = N * F;
  int npix = N * HPIX * WPIX;

  if (d_ws != nullptr && ws_size >= need_sorted) {
    float4* srecs = (float4*)(ws + offS);
    unsigned int* keys = (unsigned int*)(ws + offK);
    unsigned int* hist = (unsigned int*)(ws + offH);
    unsigned int* cursors = (unsigned int*)(ws + offC2);
    unsigned int* bins = (unsigned int*)(ws + offB2);
    int nh = N * NBUCK;
    zero_hist_kernel<<<(nh + 255) / 256, 256, 0, stream>>>(hist, nh);
    key_hist_kernel<<<(total + 255) / 256, 256, 0, stream>>>(verts, faces, keys,
                                                             hist, V, F, N);
    scan_kernel<<<N, 1024, 0, stream>>>(hist);
    scatter_kernel<<<(total + 255) / 256, 256, 0, stream>>>(verts, faces, keys,
                                                            hist, srecs, V, F, N);
    bin_kernel<<<dim3(NTILE, N), 256, 0, stream>>>(srecs, cursors, bins, F);
    raster_sorted<<<dim3(NTILE, N), 256, 0, stream>>>(srecs, bins, cursors,
                                                      verts, colors, faces,
                                                      out, V, F, C);
  } else if (d_ws != nullptr && ws_size >= offP + szP) {
    float4* recs = (float4*)ws;
    unsigned long long* packed = (unsigned long long*)(ws + offP);
    init_kernel<<<(npix + 255) / 256, 256, 0, stream>>>(packed, npix);
    prep_kernel<<<(total + 255) / 256, 256, 0, stream>>>(verts, faces, recs, V, F, N);
    raster_seg<<<dim3(16, 16, N * SEG_FLAT), block, 0, stream>>>(recs, packed, F);
    resolve_kernel<<<(npix + 255) / 256, 256, 0, stream>>>(packed, verts, colors,
                                                           faces, out, V, F, C, N);
  } else {
    raster_l<<<dim3(16, 16, N), block, 0, stream>>>(verts, colors, faces, out,
                                                    V, F, C);
  }
}

// Round 5
// 280.248 us; speedup vs baseline: 12.4740x; 1.1766x over previous
//
#include <hip/hip_runtime.h>

#define HPIX 256
#define WPIX 256
#define TSX 16
#define TSY 16
#define NTILE 256            // 16x16 tiles of 16x16 px
#define FCH 256
#define SEG_FLAT 16          // segments over all faces (fallback path)
#define NBUCK 4096           // minz counting-sort buckets over [1,2)
#define BIGF 1000000000.0f
#define EPSF 1e-8f
#define MARGIN 0.125f
#define HP_SLOP 0.0625f      // >= 4x the FP eval error bound (~0.015 w-units)
#define EPSZ 1e-4f           // early-exit slack >> depth/minz FP error (~2e-6)
#define INIT_PACK 0xFFFFFFFFFFFFFFFFull

struct FaceRec {
  float x2, y2, a0, b0, a1, b1, inv, z0, z1, z2;
  float xmin, ymin, xmax, ymax;
};

// Compute the per-face record with EXACTLY the reference's op order (no FMA).
__device__ __forceinline__ FaceRec make_rec(const float* __restrict__ vb,
                                            const int* __restrict__ faces, int f) {
#pragma clang fp contract(off)
  FaceRec r;
  int i0 = faces[f * 3 + 0], i1 = faces[f * 3 + 1], i2 = faces[f * 3 + 2];
  float x0 = vb[i0 * 3 + 0], y0 = vb[i0 * 3 + 1], z0 = vb[i0 * 3 + 2];
  float x1 = vb[i1 * 3 + 0], y1 = vb[i1 * 3 + 1], z1 = vb[i1 * 3 + 2];
  float x2 = vb[i2 * 3 + 0], y2 = vb[i2 * 3 + 1], z2 = vb[i2 * 3 + 2];
  float px0 = x0 / z0, py0 = y0 / z0;
  float px1 = x1 / z1, py1 = y1 / z1;
  float px2 = x2 / z2, py2 = y2 / z2;
  float a0 = py1 - py2, b0 = px2 - px1;   // (y1-y2), (x2-x1)
  float a1 = py2 - py0, b1 = px0 - px2;   // (y2-y0), (x0-x2)
  float dy02 = py0 - py2;
  float denom = a0 * b1 + b0 * dy02;      // (y1-y2)*(x0-x2) + (x2-x1)*(y0-y2)
  bool nz = fabsf(denom) > EPSF;
  bool valid = nz && (z0 > 0.0f) && (z1 > 0.0f) && (z2 > 0.0f);
  r.x2 = px2; r.y2 = py2; r.a0 = a0; r.b0 = b0; r.a1 = a1; r.b1 = b1;
  r.inv = valid ? 1.0f / denom : 0.0f;
  r.z0 = z0; r.z1 = z1;
  r.z2 = valid ? z2 : -1.0f;              // invalid -> depth<0 -> fails depth>0
  if (valid) {
    r.xmin = fminf(px0, fminf(px1, px2)) - MARGIN;
    r.xmax = fmaxf(px0, fmaxf(px1, px2)) + MARGIN;
    r.ymin = fminf(py0, fminf(py1, py2)) - MARGIN;
    r.ymax = fmaxf(py0, fmaxf(py1, py2)) + MARGIN;
  } else {
    r.xmin = 2.0f * BIGF; r.xmax = -2.0f * BIGF;
    r.ymin = 2.0f * BIGF; r.ymax = -2.0f * BIGF;
  }
  return r;
}

// Same arithmetic as make_rec for the validity flag + minz (must match exactly).
__device__ __forceinline__ void classify(const float* __restrict__ vb,
                                         const int* __restrict__ faces, int f,
                                         bool& valid, float& minz) {
#pragma clang fp contract(off)
  int i0 = faces[f * 3 + 0], i1 = faces[f * 3 + 1], i2 = faces[f * 3 + 2];
  float x0 = vb[i0 * 3 + 0], y0 = vb[i0 * 3 + 1], z0 = vb[i0 * 3 + 2];
  float x1 = vb[i1 * 3 + 0], y1 = vb[i1 * 3 + 1], z1 = vb[i1 * 3 + 2];
  float x2 = vb[i2 * 3 + 0], y2 = vb[i2 * 3 + 1], z2 = vb[i2 * 3 + 2];
  float px0 = x0 / z0, py0 = y0 / z0;
  float px1 = x1 / z1, py1 = y1 / z1;
  float px2 = x2 / z2, py2 = y2 / z2;
  float a0 = py1 - py2, b0 = px2 - px1;
  float b1 = px0 - px2;
  float dy02 = py0 - py2;
  float denom = a0 * b1 + b0 * dy02;
  bool nz = fabsf(denom) > EPSF;
  valid = nz && (z0 > 0.0f) && (z1 > 0.0f) && (z2 > 0.0f);
  minz = fminf(z0, fminf(z1, z2));
}

// ---------- sorted path ----------
__global__ void zero_hist_kernel(unsigned int* __restrict__ hist, int n) {
  int i = blockIdx.x * blockDim.x + threadIdx.x;
  if (i < n) hist[i] = 0u;
}

__global__ void key_hist_kernel(const float* __restrict__ verts,
                                const int* __restrict__ faces,
                                unsigned int* __restrict__ keys,
                                unsigned int* __restrict__ hist,
                                int V, int F, int NIMG) {
  int idx = blockIdx.x * blockDim.x + threadIdx.x;
  if (idx >= NIMG * F) return;
  int n = idx / F, f = idx - n * F;
  bool valid; float minz;
  classify(verts + (size_t)n * V * 3, faces, f, valid, minz);
  int b;
  if (!valid) b = NBUCK - 1;
  else {
    float t = (minz - 1.0f) * (float)NBUCK;
    b = (int)floorf(t);
    b = b < 0 ? 0 : (b > NBUCK - 1 ? NBUCK - 1 : b);
  }
  keys[idx] = (unsigned int)b;
  atomicAdd(&hist[n * NBUCK + b], 1u);
}

__global__ __launch_bounds__(1024) void scan_kernel(unsigned int* __restrict__ hist) {
  __shared__ unsigned int s[1024];
  unsigned int* h = hist + (size_t)blockIdx.x * NBUCK;
  int t = threadIdx.x;
  unsigned int v0 = h[4 * t], v1 = h[4 * t + 1], v2 = h[4 * t + 2], v3 = h[4 * t + 3];
  unsigned int sum = v0 + v1 + v2 + v3;
  s[t] = sum;
  __syncthreads();
  for (int off = 1; off < 1024; off <<= 1) {
    unsigned int x = (t >= off) ? s[t - off] : 0u;
    __syncthreads();
    s[t] += x;
    __syncthreads();
  }
  unsigned int excl = s[t] - sum;
  h[4 * t] = excl;
  h[4 * t + 1] = excl + v0;
  h[4 * t + 2] = excl + v0 + v1;
  h[4 * t + 3] = excl + v0 + v1 + v2;
}

// Scatter recs into minz-bucket-sorted order. o[2].z = key_lo (round-down
// bucket bound, <= true minz); o[2].w = original face id (bit transport).
__global__ void scatter_kernel(const float* __restrict__ verts,
                               const int* __restrict__ faces,
                               const unsigned int* __restrict__ keys,
                               unsigned int* __restrict__ hist,
                               float4* __restrict__ srecs,
                               int V, int F, int NIMG) {
  int idx = blockIdx.x * blockDim.x + threadIdx.x;
  if (idx >= NIMG * F) return;
  int n = idx / F, f = idx - n * F;
  const float* vb = verts + (size_t)n * V * 3;
  FaceRec r = make_rec(vb, faces, f);
  bool valid; float minz;
  classify(vb, faces, f, valid, minz);
  unsigned int b = keys[idx];
  // bucket 0 uses a sentinel so minz<1 robustness can't cause early-exit bugs
  float key_lo = (b == 0u) ? -3.0e38f
               : fminf(1.0f + (float)b * (1.0f / (float)NBUCK),
                       valid ? minz : 3.0e38f);
  unsigned int pos = atomicAdd(&hist[n * NBUCK + b], 1u);
  float4* o = srecs + ((size_t)n * F + pos) * 4;
  o[0] = make_float4(r.x2, r.y2, r.a0, r.b0);
  o[1] = make_float4(r.a1, r.b1, r.inv, r.z0);
  o[2] = make_float4(r.z1, r.z2, key_lo, __int_as_float(f));
  o[3] = make_float4(r.xmin, r.ymin, r.xmax, r.ymax);
}

// Order-preserving binning: iterate sorted positions j in chunks of 256;
// block-ordered compaction keeps each bin ascending in j (=> ascending key_lo).
__global__ __launch_bounds__(256) void bin_kernel(
    const float4* __restrict__ srecs, unsigned int* __restrict__ cursors,
    unsigned int* __restrict__ bins, int F) {
#pragma clang fp contract(off)
  const int t = blockIdx.x, n = blockIdx.y;
  const int tlx = t & 15, tly = t >> 4;
  const float X0 = (float)(tlx * TSX), X1 = X0 + (float)(TSX - 1);
  const float Y0 = (float)(tly * TSY), Y1 = Y0 + (float)(TSY - 1);
  __shared__ unsigned int s_cnt[4];
  __shared__ unsigned int s_cur;
  const int tid = (int)threadIdx.x;
  const int lane = tid & 63, wid = tid >> 6;
  if (tid == 0) s_cur = 0u;
  __syncthreads();
  const float4* rb = srecs + (size_t)n * F * 4;
  unsigned int* bin = bins + ((size_t)(n * NTILE + t)) * F;
  for (int base = 0; base < F; base += 256) {
    int j = base + tid;
    bool keep = false;
    if (j < F) {
      float4 D = rb[j * 4 + 3];
      keep = (D.x <= X1) && (D.z >= X0) && (D.y <= Y1) && (D.w >= Y0);
      if (keep) {
        float4 A = rb[j * 4 + 0];
        float4 B = rb[j * 4 + 1];
        float inv = B.z;
        if (fabsf(inv) <= 1.0f) {
          float m0 = -3.0e38f, m1 = -3.0e38f, m2 = -3.0e38f;
#pragma unroll
          for (int c = 0; c < 4; ++c) {
            float ccx = (c & 1) ? X1 : X0;
            float ccy = (c & 2) ? Y1 : Y0;
            float bx = ccx - A.x, by = ccy - A.y;
            float w0 = (A.z * bx + A.w * by) * inv;
            float w1 = (B.x * bx + B.y * by) * inv;
            float w2 = 1.0f - w0 - w1;
            m0 = fmaxf(m0, w0); m1 = fmaxf(m1, w1); m2 = fmaxf(m2, w2);
          }
          keep = (m0 >= -HP_SLOP) && (m1 >= -HP_SLOP) && (m2 >= -HP_SLOP);
        }
      }
    }
    unsigned long long m = __ballot(keep);
    int cw = __popcll(m);
    if (lane == 0) s_cnt[wid] = (unsigned int)cw;
    __syncthreads();
    unsigned int woff = s_cur;
    for (int w = 0; w < wid; ++w) woff += s_cnt[w];
    unsigned int tot = s_cnt[0] + s_cnt[1] + s_cnt[2] + s_cnt[3];
    if (keep) {
      int off = __popcll(m & ((1ull << lane) - 1ull));
      bin[woff + (unsigned int)off] = (unsigned int)j;
    }
    __syncthreads();             // all reads of s_cur/s_cnt done
    if (tid == 0) s_cur += tot;
  }
  __syncthreads();
  if (tid == 0) cursors[n * NTILE + t] = s_cur;
}

// Epilogue: interpolate colors for the winning face, apply any-positive mask,
// write NCHW. Recomputes weights via make_rec -> bit-identical values.
__device__ __forceinline__ void emit_pixel(float* __restrict__ out,
    const float* __restrict__ vb, const float* __restrict__ colors,
    const int* __restrict__ faces, int n, int V, int C, int bestf,
    float cx, float cy, int row, int col) {
#pragma clang fp contract(off)
  float cv[8];
#pragma unroll
  for (int ch = 0; ch < 8; ++ch) cv[ch] = 0.0f;
  if (bestf >= 0) {
    int i0 = faces[bestf * 3 + 0], i1 = faces[bestf * 3 + 1], i2 = faces[bestf * 3 + 2];
    FaceRec r = make_rec(vb, faces, bestf);
    float bx = cx - r.x2, by = cy - r.y2;
    float w0 = (r.a0 * bx + r.b0 * by) * r.inv;
    float w1 = (r.a1 * bx + r.b1 * by) * r.inv;
    float w2 = 1.0f - w0 - w1;
    const float* c0 = colors + ((size_t)n * V + i0) * C;
    const float* c1 = colors + ((size_t)n * V + i1) * C;
    const float* c2 = colors + ((size_t)n * V + i2) * C;
    for (int ch = 0; ch < C && ch < 8; ++ch)
      cv[ch] = (w0 * c0[ch] + w1 * c1[ch]) + w2 * c2[ch];
  }
  bool anyp = false;
  for (int ch = 0; ch < C && ch < 8; ++ch) anyp = anyp || (cv[ch] > 0.0f);
  float m = anyp ? 1.0f : 0.0f;
  size_t base = (size_t)n * C * HPIX * WPIX + (size_t)row * WPIX + col;
  for (int ch = 0; ch < C && ch < 8; ++ch)
    out[base + (size_t)ch * HPIX * WPIX] = cv[ch] * m;
}

#define TESTF(Ak, Bk, Zk)                                                     \
  {                                                                           \
    float bx = cx - Ak.x, by = cy - Ak.y;                                     \
    float w0 = (Ak.z * bx + Ak.w * by) * Bk.z;                                \
    float w1 = (Bk.x * bx + Bk.y * by) * Bk.z;                                \
    float w2 = 1.0f - w0 - w1;                                                \
    float depth = (w0 * Bk.w + w1 * Zk.x) + w2 * Zk.y;                        \
    bool ok = (w0 >= 0.0f) && (w1 >= 0.0f) && (w2 >= 0.0f) && (depth > 0.0f); \
    if (ok) {                                                                 \
      unsigned int forig = (unsigned int)__float_as_int(Zk.w);                \
      unsigned long long p =                                                  \
          ((unsigned long long)__float_as_uint(depth) << 32) | forig;         \
      if (p < best) { best = p; d = depth; }                                  \
    }                                                                         \
  }

// One WAVE per 8x8 pixel quadrant (64-thread workgroups, 2048 blocks):
// fine-grained scheduling hides the serial scalar-load latency and isolates
// the long uncovered-border waves. Inner loop batch-4: 12 wave-uniform
// record loads in flight per iteration, one sorted-minz exit check (on the
// batch's FIRST = smallest key_lo -> break remains conservative/correct).
__global__ __launch_bounds__(64) void raster_sorted(
    const float4* __restrict__ srecs, const unsigned int* __restrict__ bins,
    const unsigned int* __restrict__ cursors, const float* __restrict__ verts,
    const float* __restrict__ colors, const int* __restrict__ faces,
    float* __restrict__ out, int V, int F, int C) {
#pragma clang fp contract(off)
  const int bq = blockIdx.x;
  const int t = bq >> 2, quad = bq & 3;
  const int n = blockIdx.y;
  const int tlx = t & 15, tly = t >> 4;
  const int lane = (int)threadIdx.x;
  const int tx = lane & 7, ty = lane >> 3;
  const int col = tlx * TSX + (quad & 1) * 8 + tx;
  const int row = tly * TSY + (quad >> 1) * 8 + ty;
  const float cx = (float)col, cy = (float)row;
  const float4* rb = srecs + (size_t)n * F * 4;
  const unsigned int* bin = bins + ((size_t)(n * NTILE + t)) * F;
  const int cnt = (int)cursors[n * NTILE + t];
  unsigned long long best = INIT_PACK;
  float d = BIGF;
  for (int i = 0; i < cnt; i += 4) {
    int c1i = min(i + 1, cnt - 1);
    int c2i = min(i + 2, cnt - 1);
    int c3i = min(i + 3, cnt - 1);
    int j0 = (int)bin[i], j1 = (int)bin[c1i], j2 = (int)bin[c2i], j3 = (int)bin[c3i];
    float4 Z0 = rb[j0 * 4 + 2], Z1 = rb[j1 * 4 + 2];
    float4 Z2 = rb[j2 * 4 + 2], Z3 = rb[j3 * 4 + 2];
    float4 A0 = rb[j0 * 4 + 0], B0 = rb[j0 * 4 + 1];
    float4 A1 = rb[j1 * 4 + 0], B1 = rb[j1 * 4 + 1];
    float4 A2 = rb[j2 * 4 + 0], B2 = rb[j2 * 4 + 1];
    float4 A3 = rb[j3 * 4 + 0], B3 = rb[j3 * 4 + 1];
    if (__all(Z0.z > d + EPSZ)) break;   // sorted: all later faces deeper
    TESTF(A0, B0, Z0);
    if (i + 1 < cnt) TESTF(A1, B1, Z1);
    if (i + 2 < cnt) TESTF(A2, B2, Z2);
    if (i + 3 < cnt) TESTF(A3, B3, Z3);
  }
  int bestf = (best == INIT_PACK) ? -1 : (int)(unsigned int)(best & 0xFFFFFFFFull);
  emit_pixel(out, verts + (size_t)n * V * 3, colors, faces, n, V, C, bestf,
             cx, cy, row, col);
}

// ---------- fallbacks (smaller ws) ----------
__global__ void prep_kernel(const float* __restrict__ verts,
                            const int* __restrict__ faces,
                            float4* __restrict__ recs, int V, int F, int NIMG) {
  int idx = blockIdx.x * blockDim.x + threadIdx.x;
  int total = NIMG * F;
  if (idx >= total) return;
  int n = idx / F, f = idx - n * F;
  FaceRec r = make_rec(verts + (size_t)n * V * 3, faces, f);
  float4* o = recs + (size_t)idx * 4;
  o[0] = make_float4(r.x2, r.y2, r.a0, r.b0);
  o[1] = make_float4(r.a1, r.b1, r.inv, r.z0);
  o[2] = make_float4(r.z1, r.z2, 0.0f, 0.0f);
  o[3] = make_float4(r.xmin, r.ymin, r.xmax, r.ymax);
}

__global__ void init_kernel(unsigned long long* __restrict__ packed, int npix) {
  int i = blockIdx.x * blockDim.x + threadIdx.x;
  if (i < npix) packed[i] = INIT_PACK;
}

__device__ __forceinline__ void test_face(float4 A, float4 B, float4 Z, int f,
                                          float cx, float cy,
                                          unsigned long long& best) {
#pragma clang fp contract(off)
  float bx = cx - A.x, by = cy - A.y;
  float w0 = (A.z * bx + A.w * by) * B.z;
  float w1 = (B.x * bx + B.y * by) * B.z;
  float w2 = 1.0f - w0 - w1;
  float depth = (w0 * B.w + w1 * Z.x) + w2 * Z.y;
  bool ok = (w0 >= 0.0f) && (w1 >= 0.0f) && (w2 >= 0.0f) && (depth > 0.0f);
  if (ok) {
    unsigned long long p =
        ((unsigned long long)__float_as_uint(depth) << 32) | (unsigned int)f;
    best = p < best ? p : best;
  }
}

__global__ __launch_bounds__(256) void raster_seg(
    const float4* __restrict__ recs, unsigned long long* __restrict__ packed,
    int F) {
  const int tx = threadIdx.x, ty = threadIdx.y;
  const int n = blockIdx.z / SEG_FLAT, s = blockIdx.z % SEG_FLAT;
  const int col = blockIdx.x * TSX + tx, row = blockIdx.y * TSY + ty;
  const float cx = (float)col, cy = (float)row;
  const float tX0 = (float)(blockIdx.x * TSX), tX1 = tX0 + (float)(TSX - 1);
  const float tY0 = (float)(blockIdx.y * TSY), tY1 = tY0 + (float)(TSY - 1);
  const float4* rb = recs + (size_t)n * F * 4;
  unsigned long long best = INIT_PACK;
  for (int f = s; f < F; f += SEG_FLAT) {
    float4 bb = rb[f * 4 + 3];
    if (bb.x > tX1 || bb.z < tX0 || bb.y > tY1 || bb.w < tY0) continue;
    float4 A = rb[f * 4 + 0];
    float4 B = rb[f * 4 + 1];
    float4 Z = rb[f * 4 + 2];
    test_face(A, B, Z, f, cx, cy, best);
  }
  if (best != INIT_PACK)
    atomicMin(&packed[(size_t)n * (HPIX * WPIX) + row * WPIX + col], best);
}

__global__ __launch_bounds__(256) void resolve_kernel(
    const unsigned long long* __restrict__ packed,
    const float* __restrict__ verts, const float* __restrict__ colors,
    const int* __restrict__ faces, float* __restrict__ out,
    int V, int F, int C, int NIMG) {
  int i = blockIdx.x * blockDim.x + threadIdx.x;
  int total = NIMG * HPIX * WPIX;
  if (i >= total) return;
  int n = i / (HPIX * WPIX);
  int pix = i - n * (HPIX * WPIX);
  int row = pix >> 8, col = pix & 255;
  unsigned long long p = packed[i];
  int bestf = (p == INIT_PACK) ? -1 : (int)(unsigned int)(p & 0xFFFFFFFFull);
  emit_pixel(out, verts + (size_t)n * V * 3, colors, faces, n, V, C, bestf,
             (float)col, (float)row, row, col);
}

__global__ __launch_bounds__(256) void raster_l(const float* __restrict__ verts,
    const float* __restrict__ colors, const int* __restrict__ faces,
    float* __restrict__ out, int V, int F, int C) {
#pragma clang fp contract(off)
  __shared__ float4 sA[FCH], sB[FCH], sZ[FCH], sD[FCH];
  const int n = blockIdx.z;
  const int tx = threadIdx.x, ty = threadIdx.y;
  const int tid = ty * TSX + tx;
  const int col = blockIdx.x * TSX + tx;
  const int row = blockIdx.y * TSY + ty;
  const float cx = (float)col, cy = (float)row;
  const float tX0 = (float)(blockIdx.x * TSX), tX1 = tX0 + (float)(TSX - 1);
  const float tY0 = (float)(blockIdx.y * TSY), tY1 = tY0 + (float)(TSY - 1);
  const float* vb = verts + (size_t)n * V * 3;
  float bestd = BIGF;
  int bestf = -1;
  for (int base = 0; base < F; base += FCH) {
    int cnt = min(FCH, F - base);
    if (tid < cnt) {
      FaceRec r = make_rec(vb, faces, base + tid);
      sA[tid] = make_float4(r.x2, r.y2, r.a0, r.b0);
      sB[tid] = make_float4(r.a1, r.b1, r.inv, r.z0);
      sZ[tid] = make_float4(r.z1, r.z2, 0.0f, 0.0f);
      sD[tid] = make_float4(r.xmin, r.ymin, r.xmax, r.ymax);
    }
    __syncthreads();
    for (int j = 0; j < cnt; ++j) {
      float4 bb = sD[j];
      if (bb.x > tX1 || bb.z < tX0 || bb.y > tY1 || bb.w < tY0) continue;
      float4 A = sA[j];
      float4 B = sB[j];
      float4 Z = sZ[j];
      float bx = cx - A.x, by = cy - A.y;
      float w0 = (A.z * bx + A.w * by) * B.z;
      float w1 = (B.x * bx + B.y * by) * B.z;
      float w2 = 1.0f - w0 - w1;
      float depth = (w0 * B.w + w1 * Z.x) + w2 * Z.y;
      bool ok = (w0 >= 0.0f) && (w1 >= 0.0f) && (w2 >= 0.0f) && (depth > 0.0f);
      float d = ok ? depth : BIGF;
      if (d < bestd) { bestd = d; bestf = base + j; }
    }
    __syncthreads();
  }
  emit_pixel(out, vb, colors, faces, n, V, C, bestf, cx, cy, row, col);
}

extern "C" void kernel_launch(void* const* d_in, const int* in_sizes, int n_in,
                              void* d_out, int out_size, void* d_ws, size_t ws_size,
                              hipStream_t stream) {
  const float* verts = (const float*)d_in[0];
  const float* colors = (const float*)d_in[1];
  const int* faces = (const int*)d_in[2];
  float* out = (float*)d_out;
  long long s0 = in_sizes[0], s1 = in_sizes[1], s2 = in_sizes[2];
  int C = (int)((3LL * s1) / s0);
  if (C < 1) C = 1;
  int NC = out_size / (HPIX * WPIX);
  int N = NC / C;
  if (N < 1) N = 1;
  int V = (int)(s0 / (3LL * N));
  int F = (int)(s2 / 3);

  // sorted-path ws layout: srecs | keys | hist | cursors | bins
  size_t offS = 0;
  size_t szS = (size_t)N * F * 4 * sizeof(float4);
  size_t offK = (offS + szS + 255) & ~(size_t)255;
  size_t szK = (size_t)N * F * sizeof(unsigned int);
  size_t offH = (offK + szK + 255) & ~(size_t)255;
  size_t szH = (size_t)N * NBUCK * sizeof(unsigned int);
  size_t offC2 = (offH + szH + 255) & ~(size_t)255;
  size_t szC2 = (size_t)N * NTILE * sizeof(unsigned int);
  size_t offB2 = (offC2 + szC2 + 255) & ~(size_t)255;
  size_t szB2 = (size_t)N * NTILE * (size_t)F * sizeof(unsigned int);
  size_t need_sorted = offB2 + szB2;

  // fallback layout: recs | packed
  size_t szR = (size_t)N * F * 4 * sizeof(float4);
  size_t offP = (szR + 255) & ~(size_t)255;
  size_t szP = (size_t)N * HPIX * WPIX * sizeof(unsigned long long);

  dim3 block(TSX, TSY);
  char* ws = (char*)d_ws;
  int total = N * F;
  int npix = N * HPIX * WPIX;

  if (d_ws != nullptr && ws_size >= need_sorted) {
    float4* srecs = (float4*)(ws + offS);
    unsigned int* keys = (unsigned int*)(ws + offK);
    unsigned int* hist = (unsigned int*)(ws + offH);
    unsigned int* cursors = (unsigned int*)(ws + offC2);
    unsigned int* bins = (unsigned int*)(ws + offB2);
    int nh = N * NBUCK;
    zero_hist_kernel<<<(nh + 255) / 256, 256, 0, stream>>>(hist, nh);
    key_hist_kernel<<<(total + 255) / 256, 256, 0, stream>>>(verts, faces, keys,
                                                             hist, V, F, N);
    scan_kernel<<<N, 1024, 0, stream>>>(hist);
    scatter_kernel<<<(total + 255) / 256, 256, 0, stream>>>(verts, faces, keys,
                                                            hist, srecs, V, F, N);
    bin_kernel<<<dim3(NTILE, N), 256, 0, stream>>>(srecs, cursors, bins, F);
    raster_sorted<<<dim3(NTILE * 4, N), 64, 0, stream>>>(srecs, bins, cursors,
                                                         verts, colors, faces,
                                                         out, V, F, C);
  } else if (d_ws != nullptr && ws_size >= offP + szP) {
    float4* recs = (float4*)ws;
    unsigned long long* packed = (unsigned long long*)(ws + offP);
    init_kernel<<<(npix + 255) / 256, 256, 0, stream>>>(packed, npix);
    prep_kernel<<<(total + 255) / 256, 256, 0, stream>>>(verts, faces, recs, V, F, N);
    raster_seg<<<dim3(16, 16, N * SEG_FLAT), block, 0, stream>>>(recs, packed, F);
    resolve_kernel<<<(npix + 255) / 256, 256, 0, stream>>>(packed, verts, colors,
                                                           faces, out, V, F, C, N);
  } else {
    raster_l<<<dim3(16, 16, N), block, 0, stream>>>(verts, colors, faces, out,
                                                    V, F, C);
  }
}

// Round 6
// 267.431 us; speedup vs baseline: 13.0718x; 1.0479x over previous
//
#include <hip/hip_runtime.h>

#define HPIX 256
#define WPIX 256
#define TSX 16
#define TSY 16
#define NTILE 256            // 16x16 tiles of 16x16 px
#define FCH 256
#define SEG_FLAT 16          // segments over all faces (fallback path)
#define NBUCK 4096           // minz counting-sort buckets over [1,2)
#define RSEG 8               // waves (bin segments) per quadrant block
#define BIGF 1000000000.0f
#define EPSF 1e-8f
#define MARGIN 0.125f
#define HP_SLOP 0.0625f      // >= 4x the FP eval error bound (~0.015 w-units)
#define EPSZ 1e-4f           // early-exit slack >> depth/minz FP error (~2e-6)
#define INIT_PACK 0xFFFFFFFFFFFFFFFFull

struct FaceRec {
  float x2, y2, a0, b0, a1, b1, inv, z0, z1, z2;
  float xmin, ymin, xmax, ymax;
};

// Compute the per-face record with EXACTLY the reference's op order (no FMA).
__device__ __forceinline__ FaceRec make_rec(const float* __restrict__ vb,
                                            const int* __restrict__ faces, int f) {
#pragma clang fp contract(off)
  FaceRec r;
  int i0 = faces[f * 3 + 0], i1 = faces[f * 3 + 1], i2 = faces[f * 3 + 2];
  float x0 = vb[i0 * 3 + 0], y0 = vb[i0 * 3 + 1], z0 = vb[i0 * 3 + 2];
  float x1 = vb[i1 * 3 + 0], y1 = vb[i1 * 3 + 1], z1 = vb[i1 * 3 + 2];
  float x2 = vb[i2 * 3 + 0], y2 = vb[i2 * 3 + 1], z2 = vb[i2 * 3 + 2];
  float px0 = x0 / z0, py0 = y0 / z0;
  float px1 = x1 / z1, py1 = y1 / z1;
  float px2 = x2 / z2, py2 = y2 / z2;
  float a0 = py1 - py2, b0 = px2 - px1;   // (y1-y2), (x2-x1)
  float a1 = py2 - py0, b1 = px0 - px2;   // (y2-y0), (x0-x2)
  float dy02 = py0 - py2;
  float denom = a0 * b1 + b0 * dy02;      // (y1-y2)*(x0-x2) + (x2-x1)*(y0-y2)
  bool nz = fabsf(denom) > EPSF;
  bool valid = nz && (z0 > 0.0f) && (z1 > 0.0f) && (z2 > 0.0f);
  r.x2 = px2; r.y2 = py2; r.a0 = a0; r.b0 = b0; r.a1 = a1; r.b1 = b1;
  r.inv = valid ? 1.0f / denom : 0.0f;
  r.z0 = z0; r.z1 = z1;
  r.z2 = valid ? z2 : -1.0f;              // invalid -> depth<0 -> fails depth>0
  if (valid) {
    r.xmin = fminf(px0, fminf(px1, px2)) - MARGIN;
    r.xmax = fmaxf(px0, fmaxf(px1, px2)) + MARGIN;
    r.ymin = fminf(py0, fminf(py1, py2)) - MARGIN;
    r.ymax = fmaxf(py0, fmaxf(py1, py2)) + MARGIN;
  } else {
    r.xmin = 2.0f * BIGF; r.xmax = -2.0f * BIGF;
    r.ymin = 2.0f * BIGF; r.ymax = -2.0f * BIGF;
  }
  return r;
}

// Same arithmetic as make_rec for the validity flag + minz (must match exactly).
__device__ __forceinline__ void classify(const float* __restrict__ vb,
                                         const int* __restrict__ faces, int f,
                                         bool& valid, float& minz) {
#pragma clang fp contract(off)
  int i0 = faces[f * 3 + 0], i1 = faces[f * 3 + 1], i2 = faces[f * 3 + 2];
  float x0 = vb[i0 * 3 + 0], y0 = vb[i0 * 3 + 1], z0 = vb[i0 * 3 + 2];
  float x1 = vb[i1 * 3 + 0], y1 = vb[i1 * 3 + 1], z1 = vb[i1 * 3 + 2];
  float x2 = vb[i2 * 3 + 0], y2 = vb[i2 * 3 + 1], z2 = vb[i2 * 3 + 2];
  float px0 = x0 / z0, py0 = y0 / z0;
  float px1 = x1 / z1, py1 = y1 / z1;
  float px2 = x2 / z2, py2 = y2 / z2;
  float a0 = py1 - py2, b0 = px2 - px1;
  float b1 = px0 - px2;
  float dy02 = py0 - py2;
  float denom = a0 * b1 + b0 * dy02;
  bool nz = fabsf(denom) > EPSF;
  valid = nz && (z0 > 0.0f) && (z1 > 0.0f) && (z2 > 0.0f);
  minz = fminf(z0, fminf(z1, z2));
}

// ---------- sorted path ----------
__global__ void zero_hist_kernel(unsigned int* __restrict__ hist, int n) {
  int i = blockIdx.x * blockDim.x + threadIdx.x;
  if (i < n) hist[i] = 0u;
}

__global__ void key_hist_kernel(const float* __restrict__ verts,
                                const int* __restrict__ faces,
                                unsigned int* __restrict__ keys,
                                unsigned int* __restrict__ hist,
                                int V, int F, int NIMG) {
  int idx = blockIdx.x * blockDim.x + threadIdx.x;
  if (idx >= NIMG * F) return;
  int n = idx / F, f = idx - n * F;
  bool valid; float minz;
  classify(verts + (size_t)n * V * 3, faces, f, valid, minz);
  int b;
  if (!valid) b = NBUCK - 1;
  else {
    float t = (minz - 1.0f) * (float)NBUCK;
    b = (int)floorf(t);
    b = b < 0 ? 0 : (b > NBUCK - 1 ? NBUCK - 1 : b);
  }
  keys[idx] = (unsigned int)b;
  atomicAdd(&hist[n * NBUCK + b], 1u);
}

__global__ __launch_bounds__(1024) void scan_kernel(unsigned int* __restrict__ hist) {
  __shared__ unsigned int s[1024];
  unsigned int* h = hist + (size_t)blockIdx.x * NBUCK;
  int t = threadIdx.x;
  unsigned int v0 = h[4 * t], v1 = h[4 * t + 1], v2 = h[4 * t + 2], v3 = h[4 * t + 3];
  unsigned int sum = v0 + v1 + v2 + v3;
  s[t] = sum;
  __syncthreads();
  for (int off = 1; off < 1024; off <<= 1) {
    unsigned int x = (t >= off) ? s[t - off] : 0u;
    __syncthreads();
    s[t] += x;
    __syncthreads();
  }
  unsigned int excl = s[t] - sum;
  h[4 * t] = excl;
  h[4 * t + 1] = excl + v0;
  h[4 * t + 2] = excl + v0 + v1;
  h[4 * t + 3] = excl + v0 + v1 + v2;
}

// Scatter recs into minz-bucket-sorted order. o[2].z = key_lo (round-down
// bucket bound, <= true minz); o[2].w = original face id (bit transport).
__global__ void scatter_kernel(const float* __restrict__ verts,
                               const int* __restrict__ faces,
                               const unsigned int* __restrict__ keys,
                               unsigned int* __restrict__ hist,
                               float4* __restrict__ srecs,
                               int V, int F, int NIMG) {
  int idx = blockIdx.x * blockDim.x + threadIdx.x;
  if (idx >= NIMG * F) return;
  int n = idx / F, f = idx - n * F;
  const float* vb = verts + (size_t)n * V * 3;
  FaceRec r = make_rec(vb, faces, f);
  bool valid; float minz;
  classify(vb, faces, f, valid, minz);
  unsigned int b = keys[idx];
  // bucket 0 uses a sentinel so minz<1 robustness can't cause early-exit bugs
  float key_lo = (b == 0u) ? -3.0e38f
               : fminf(1.0f + (float)b * (1.0f / (float)NBUCK),
                       valid ? minz : 3.0e38f);
  unsigned int pos = atomicAdd(&hist[n * NBUCK + b], 1u);
  float4* o = srecs + ((size_t)n * F + pos) * 4;
  o[0] = make_float4(r.x2, r.y2, r.a0, r.b0);
  o[1] = make_float4(r.a1, r.b1, r.inv, r.z0);
  o[2] = make_float4(r.z1, r.z2, key_lo, __int_as_float(f));
  o[3] = make_float4(r.xmin, r.ymin, r.xmax, r.ymax);
}

// Order-preserving binning: iterate sorted positions j in chunks of 256;
// block-ordered compaction keeps each bin ascending in j (=> ascending key_lo).
__global__ __launch_bounds__(256) void bin_kernel(
    const float4* __restrict__ srecs, unsigned int* __restrict__ cursors,
    unsigned int* __restrict__ bins, int F) {
#pragma clang fp contract(off)
  const int t = blockIdx.x, n = blockIdx.y;
  const int tlx = t & 15, tly = t >> 4;
  const float X0 = (float)(tlx * TSX), X1 = X0 + (float)(TSX - 1);
  const float Y0 = (float)(tly * TSY), Y1 = Y0 + (float)(TSY - 1);
  __shared__ unsigned int s_cnt[4];
  __shared__ unsigned int s_cur;
  const int tid = (int)threadIdx.x;
  const int lane = tid & 63, wid = tid >> 6;
  if (tid == 0) s_cur = 0u;
  __syncthreads();
  const float4* rb = srecs + (size_t)n * F * 4;
  unsigned int* bin = bins + ((size_t)(n * NTILE + t)) * F;
  for (int base = 0; base < F; base += 256) {
    int j = base + tid;
    bool keep = false;
    if (j < F) {
      float4 D = rb[j * 4 + 3];
      keep = (D.x <= X1) && (D.z >= X0) && (D.y <= Y1) && (D.w >= Y0);
      if (keep) {
        float4 A = rb[j * 4 + 0];
        float4 B = rb[j * 4 + 1];
        float inv = B.z;
        if (fabsf(inv) <= 1.0f) {
          float m0 = -3.0e38f, m1 = -3.0e38f, m2 = -3.0e38f;
#pragma unroll
          for (int c = 0; c < 4; ++c) {
            float ccx = (c & 1) ? X1 : X0;
            float ccy = (c & 2) ? Y1 : Y0;
            float bx = ccx - A.x, by = ccy - A.y;
            float w0 = (A.z * bx + A.w * by) * inv;
            float w1 = (B.x * bx + B.y * by) * inv;
            float w2 = 1.0f - w0 - w1;
            m0 = fmaxf(m0, w0); m1 = fmaxf(m1, w1); m2 = fmaxf(m2, w2);
          }
          keep = (m0 >= -HP_SLOP) && (m1 >= -HP_SLOP) && (m2 >= -HP_SLOP);
        }
      }
    }
    unsigned long long m = __ballot(keep);
    int cw = __popcll(m);
    if (lane == 0) s_cnt[wid] = (unsigned int)cw;
    __syncthreads();
    unsigned int woff = s_cur;
    for (int w = 0; w < wid; ++w) woff += s_cnt[w];
    unsigned int tot = s_cnt[0] + s_cnt[1] + s_cnt[2] + s_cnt[3];
    if (keep) {
      int off = __popcll(m & ((1ull << lane) - 1ull));
      bin[woff + (unsigned int)off] = (unsigned int)j;
    }
    __syncthreads();             // all reads of s_cur/s_cnt done
    if (tid == 0) s_cur += tot;
  }
  __syncthreads();
  if (tid == 0) cursors[n * NTILE + t] = s_cur;
}

// Epilogue: interpolate colors for the winning face, apply any-positive mask,
// write NCHW. Recomputes weights via make_rec -> bit-identical values.
__device__ __forceinline__ void emit_pixel(float* __restrict__ out,
    const float* __restrict__ vb, const float* __restrict__ colors,
    const int* __restrict__ faces, int n, int V, int C, int bestf,
    float cx, float cy, int row, int col) {
#pragma clang fp contract(off)
  float cv[8];
#pragma unroll
  for (int ch = 0; ch < 8; ++ch) cv[ch] = 0.0f;
  if (bestf >= 0) {
    int i0 = faces[bestf * 3 + 0], i1 = faces[bestf * 3 + 1], i2 = faces[bestf * 3 + 2];
    FaceRec r = make_rec(vb, faces, bestf);
    float bx = cx - r.x2, by = cy - r.y2;
    float w0 = (r.a0 * bx + r.b0 * by) * r.inv;
    float w1 = (r.a1 * bx + r.b1 * by) * r.inv;
    float w2 = 1.0f - w0 - w1;
    const float* c0 = colors + ((size_t)n * V + i0) * C;
    const float* c1 = colors + ((size_t)n * V + i1) * C;
    const float* c2 = colors + ((size_t)n * V + i2) * C;
    for (int ch = 0; ch < C && ch < 8; ++ch)
      cv[ch] = (w0 * c0[ch] + w1 * c1[ch]) + w2 * c2[ch];
  }
  bool anyp = false;
  for (int ch = 0; ch < C && ch < 8; ++ch) anyp = anyp || (cv[ch] > 0.0f);
  float m = anyp ? 1.0f : 0.0f;
  size_t base = (size_t)n * C * HPIX * WPIX + (size_t)row * WPIX + col;
  for (int ch = 0; ch < C && ch < 8; ++ch)
    out[base + (size_t)ch * HPIX * WPIX] = cv[ch] * m;
}

#define TESTF(Ak, Bk, Zk)                                                     \
  {                                                                           \
    float bx = cx - Ak.x, by = cy - Ak.y;                                     \
    float w0 = (Ak.z * bx + Ak.w * by) * Bk.z;                                \
    float w1 = (Bk.x * bx + Bk.y * by) * Bk.z;                                \
    float w2 = 1.0f - w0 - w1;                                                \
    float depth = (w0 * Bk.w + w1 * Zk.x) + w2 * Zk.y;                        \
    bool ok = (w0 >= 0.0f) && (w1 >= 0.0f) && (w2 >= 0.0f) && (depth > 0.0f); \
    if (ok) {                                                                 \
      unsigned int forig = (unsigned int)__float_as_int(Zk.w);                \
      unsigned long long p =                                                  \
          ((unsigned long long)__float_as_uint(depth) << 32) | forig;         \
      if (p < best) { best = p; d = depth; }                                  \
    }                                                                         \
  }

// 512 threads = 8 waves per 8x8 quadrant. Wave w scans sorted-bin subsequence
// {w, w+RSEG, ...} (ascending key_lo) with its own conservative early exit:
// skipped faces have depth >= key_lo - 2e-6 > d_local, so neither the min nor
// the index tie-break can change. LDS reduce across waves, wave 0 emits.
__global__ __launch_bounds__(512) void raster_sorted(
    const float4* __restrict__ srecs, const unsigned int* __restrict__ bins,
    const unsigned int* __restrict__ cursors, const float* __restrict__ verts,
    const float* __restrict__ colors, const int* __restrict__ faces,
    float* __restrict__ out, int V, int F, int C) {
#pragma clang fp contract(off)
  __shared__ unsigned long long sbest[RSEG][64];
  const int bq = blockIdx.x;
  const int t = bq >> 2, quad = bq & 3;
  const int n = blockIdx.y;
  const int tlx = t & 15, tly = t >> 4;
  const int tid = (int)threadIdx.x;
  const int wave = tid >> 6, lane = tid & 63;
  const int tx = lane & 7, ty = lane >> 3;
  const int col = tlx * TSX + (quad & 1) * 8 + tx;
  const int row = tly * TSY + (quad >> 1) * 8 + ty;
  const float cx = (float)col, cy = (float)row;
  const float4* rb = srecs + (size_t)n * F * 4;
  const unsigned int* bin = bins + ((size_t)(n * NTILE + t)) * F;
  const int cnt = (int)cursors[n * NTILE + t];
  unsigned long long best = INIT_PACK;
  float d = BIGF;
  for (int i0 = wave; i0 < cnt; i0 += 4 * RSEG) {
    int i1 = i0 + RSEG, i2 = i0 + 2 * RSEG, i3 = i0 + 3 * RSEG;
    int c1i = i1 < cnt ? i1 : cnt - 1;
    int c2i = i2 < cnt ? i2 : cnt - 1;
    int c3i = i3 < cnt ? i3 : cnt - 1;
    int j0 = (int)bin[i0], j1 = (int)bin[c1i], j2 = (int)bin[c2i], j3 = (int)bin[c3i];
    float4 Z0 = rb[j0 * 4 + 2], Z1 = rb[j1 * 4 + 2];
    float4 Z2 = rb[j2 * 4 + 2], Z3 = rb[j3 * 4 + 2];
    float4 A0 = rb[j0 * 4 + 0], B0 = rb[j0 * 4 + 1];
    float4 A1 = rb[j1 * 4 + 0], B1 = rb[j1 * 4 + 1];
    float4 A2 = rb[j2 * 4 + 0], B2 = rb[j2 * 4 + 1];
    float4 A3 = rb[j3 * 4 + 0], B3 = rb[j3 * 4 + 1];
    if (__all(Z0.z > d + EPSZ)) break;   // sorted: all later faces deeper
    TESTF(A0, B0, Z0);
    if (i1 < cnt) TESTF(A1, B1, Z1);
    if (i2 < cnt) TESTF(A2, B2, Z2);
    if (i3 < cnt) TESTF(A3, B3, Z3);
  }
  sbest[wave][lane] = best;
  __syncthreads();
  if (tid < 64) {
    unsigned long long b = sbest[0][lane];
#pragma unroll
    for (int w = 1; w < RSEG; ++w) {
      unsigned long long v = sbest[w][lane];
      b = v < b ? v : b;
    }
    int bestf = (b == INIT_PACK) ? -1 : (int)(unsigned int)(b & 0xFFFFFFFFull);
    emit_pixel(out, verts + (size_t)n * V * 3, colors, faces, n, V, C, bestf,
               cx, cy, row, col);
  }
}

// ---------- fallbacks (smaller ws) ----------
__global__ void prep_kernel(const float* __restrict__ verts,
                            const int* __restrict__ faces,
                            float4* __restrict__ recs, int V, int F, int NIMG) {
  int idx = blockIdx.x * blockDim.x + threadIdx.x;
  int total = NIMG * F;
  if (idx >= total) return;
  int n = idx / F, f = idx - n * F;
  FaceRec r = make_rec(verts + (size_t)n * V * 3, faces, f);
  float4* o = recs + (size_t)idx * 4;
  o[0] = make_float4(r.x2, r.y2, r.a0, r.b0);
  o[1] = make_float4(r.a1, r.b1, r.inv, r.z0);
  o[2] = make_float4(r.z1, r.z2, 0.0f, 0.0f);
  o[3] = make_float4(r.xmin, r.ymin, r.xmax, r.ymax);
}

__global__ void init_kernel(unsigned long long* __restrict__ packed, int npix) {
  int i = blockIdx.x * blockDim.x + threadIdx.x;
  if (i < npix) packed[i] = INIT_PACK;
}

__device__ __forceinline__ void test_face(float4 A, float4 B, float4 Z, int f,
                                          float cx, float cy,
                                          unsigned long long& best) {
#pragma clang fp contract(off)
  float bx = cx - A.x, by = cy - A.y;
  float w0 = (A.z * bx + A.w * by) * B.z;
  float w1 = (B.x * bx + B.y * by) * B.z;
  float w2 = 1.0f - w0 - w1;
  float depth = (w0 * B.w + w1 * Z.x) + w2 * Z.y;
  bool ok = (w0 >= 0.0f) && (w1 >= 0.0f) && (w2 >= 0.0f) && (depth > 0.0f);
  if (ok) {
    unsigned long long p =
        ((unsigned long long)__float_as_uint(depth) << 32) | (unsigned int)f;
    best = p < best ? p : best;
  }
}

__global__ __launch_bounds__(256) void raster_seg(
    const float4* __restrict__ recs, unsigned long long* __restrict__ packed,
    int F) {
  const int tx = threadIdx.x, ty = threadIdx.y;
  const int n = blockIdx.z / SEG_FLAT, s = blockIdx.z % SEG_FLAT;
  const int col = blockIdx.x * TSX + tx, row = blockIdx.y * TSY + ty;
  const float cx = (float)col, cy = (float)row;
  const float tX0 = (float)(blockIdx.x * TSX), tX1 = tX0 + (float)(TSX - 1);
  const float tY0 = (float)(blockIdx.y * TSY), tY1 = tY0 + (float)(TSY - 1);
  const float4* rb = recs + (size_t)n * F * 4;
  unsigned long long best = INIT_PACK;
  for (int f = s; f < F; f += SEG_FLAT) {
    float4 bb = rb[f * 4 + 3];
    if (bb.x > tX1 || bb.z < tX0 || bb.y > tY1 || bb.w < tY0) continue;
    float4 A = rb[f * 4 + 0];
    float4 B = rb[f * 4 + 1];
    float4 Z = rb[f * 4 + 2];
    test_face(A, B, Z, f, cx, cy, best);
  }
  if (best != INIT_PACK)
    atomicMin(&packed[(size_t)n * (HPIX * WPIX) + row * WPIX + col], best);
}

__global__ __launch_bounds__(256) void resolve_kernel(
    const unsigned long long* __restrict__ packed,
    const float* __restrict__ verts, const float* __restrict__ colors,
    const int* __restrict__ faces, float* __restrict__ out,
    int V, int F, int C, int NIMG) {
  int i = blockIdx.x * blockDim.x + threadIdx.x;
  int total = NIMG * HPIX * WPIX;
  if (i >= total) return;
  int n = i / (HPIX * WPIX);
  int pix = i - n * (HPIX * WPIX);
  int row = pix >> 8, col = pix & 255;
  unsigned long long p = packed[i];
  int bestf = (p == INIT_PACK) ? -1 : (int)(unsigned int)(p & 0xFFFFFFFFull);
  emit_pixel(out, verts + (size_t)n * V * 3, colors, faces, n, V, C, bestf,
             (float)col, (float)row, row, col);
}

__global__ __launch_bounds__(256) void raster_l(const float* __restrict__ verts,
    const float* __restrict__ colors, const int* __restrict__ faces,
    float* __restrict__ out, int V, int F, int C) {
#pragma clang fp contract(off)
  __shared__ float4 sA[FCH], sB[FCH], sZ[FCH], sD[FCH];
  const int n = blockIdx.z;
  const int tx = threadIdx.x, ty = threadIdx.y;
  const int tid = ty * TSX + tx;
  const int col = blockIdx.x * TSX + tx;
  const int row = blockIdx.y * TSY + ty;
  const float cx = (float)col, cy = (float)row;
  const float tX0 = (float)(blockIdx.x * TSX), tX1 = tX0 + (float)(TSX - 1);
  const float tY0 = (float)(blockIdx.y * TSY), tY1 = tY0 + (float)(TSY - 1);
  const float* vb = verts + (size_t)n * V * 3;
  float bestd = BIGF;
  int bestf = -1;
  for (int base = 0; base < F; base += FCH) {
    int cnt = min(FCH, F - base);
    if (tid < cnt) {
      FaceRec r = make_rec(vb, faces, base + tid);
      sA[tid] = make_float4(r.x2, r.y2, r.a0, r.b0);
      sB[tid] = make_float4(r.a1, r.b1, r.inv, r.z0);
      sZ[tid] = make_float4(r.z1, r.z2, 0.0f, 0.0f);
      sD[tid] = make_float4(r.xmin, r.ymin, r.xmax, r.ymax);
    }
    __syncthreads();
    for (int j = 0; j < cnt; ++j) {
      float4 bb = sD[j];
      if (bb.x > tX1 || bb.z < tX0 || bb.y > tY1 || bb.w < tY0) continue;
      float4 A = sA[j];
      float4 B = sB[j];
      float4 Z = sZ[j];
      float bx = cx - A.x, by = cy - A.y;
      float w0 = (A.z * bx + A.w * by) * B.z;
      float w1 = (B.x * bx + B.y * by) * B.z;
      float w2 = 1.0f - w0 - w1;
      float depth = (w0 * B.w + w1 * Z.x) + w2 * Z.y;
      bool ok = (w0 >= 0.0f) && (w1 >= 0.0f) && (w2 >= 0.0f) && (depth > 0.0f);
      float d = ok ? depth : BIGF;
      if (d < bestd) { bestd = d; bestf = base + j; }
    }
    __syncthreads();
  }
  emit_pixel(out, vb, colors, faces, n, V, C, bestf, cx, cy, row, col);
}

extern "C" void kernel_launch(void* const* d_in, const int* in_sizes, int n_in,
                              void* d_out, int out_size, void* d_ws, size_t ws_size,
                              hipStream_t stream) {
  const float* verts = (const float*)d_in[0];
  const float* colors = (const float*)d_in[1];
  const int* faces = (const int*)d_in[2];
  float* out = (float*)d_out;
  long long s0 = in_sizes[0], s1 = in_sizes[1], s2 = in_sizes[2];
  int C = (int)((3LL * s1) / s0);
  if (C < 1) C = 1;
  int NC = out_size / (HPIX * WPIX);
  int N = NC / C;
  if (N < 1) N = 1;
  int V = (int)(s0 / (3LL * N));
  int F = (int)(s2 / 3);

  // sorted-path ws layout: srecs | keys | hist | cursors | bins
  size_t offS = 0;
  size_t szS = (size_t)N * F * 4 * sizeof(float4);
  size_t offK = (offS + szS + 255) & ~(size_t)255;
  size_t szK = (size_t)N * F * sizeof(unsigned int);
  size_t offH = (offK + szK + 255) & ~(size_t)255;
  size_t szH = (size_t)N * NBUCK * sizeof(unsigned int);
  size_t offC2 = (offH + szH + 255) & ~(size_t)255;
  size_t szC2 = (size_t)N * NTILE * sizeof(unsigned int);
  size_t offB2 = (offC2 + szC2 + 255) & ~(size_t)255;
  size_t szB2 = (size_t)N * NTILE * (size_t)F * sizeof(unsigned int);
  size_t need_sorted = offB2 + szB2;

  // fallback layout: recs | packed
  size_t szR = (size_t)N * F * 4 * sizeof(float4);
  size_t offP = (szR + 255) & ~(size_t)255;
  size_t szP = (size_t)N * HPIX * WPIX * sizeof(unsigned long long);

  dim3 block(TSX, TSY);
  char* ws = (char*)d_ws;
  int total = N * F;
  int npix = N * HPIX * WPIX;

  if (d_ws != nullptr && ws_size >= need_sorted) {
    float4* srecs = (float4*)(ws + offS);
    unsigned int* keys = (unsigned int*)(ws + offK);
    unsigned int* hist = (unsigned int*)(ws + offH);
    unsigned int* cursors = (unsigned int*)(ws + offC2);
    unsigned int* bins = (unsigned int*)(ws + offB2);
    int nh = N * NBUCK;
    zero_hist_kernel<<<(nh + 255) / 256, 256, 0, stream>>>(hist, nh);
    key_hist_kernel<<<(total + 255) / 256, 256, 0, stream>>>(verts, faces, keys,
                                                             hist, V, F, N);
    scan_kernel<<<N, 1024, 0, stream>>>(hist);
    scatter_kernel<<<(total + 255) / 256, 256, 0, stream>>>(verts, faces, keys,
                                                            hist, srecs, V, F, N);
    bin_kernel<<<dim3(NTILE, N), 256, 0, stream>>>(srecs, cursors, bins, F);
    raster_sorted<<<dim3(NTILE * 4, N), 512, 0, stream>>>(srecs, bins, cursors,
                                                          verts, colors, faces,
                                                          out, V, F, C);
  } else if (d_ws != nullptr && ws_size >= offP + szP) {
    float4* recs = (float4*)ws;
    unsigned long long* packed = (unsigned long long*)(ws + offP);
    init_kernel<<<(npix + 255) / 256, 256, 0, stream>>>(packed, npix);
    prep_kernel<<<(total + 255) / 256, 256, 0, stream>>>(verts, faces, recs, V, F, N);
    raster_seg<<<dim3(16, 16, N * SEG_FLAT), block, 0, stream>>>(recs, packed, F);
    resolve_kernel<<<(npix + 255) / 256, 256, 0, stream>>>(packed, verts, colors,
                                                           faces, out, V, F, C, N);
  } else {
    raster_l<<<dim3(16, 16, N), block, 0, stream>>>(verts, colors, faces, out,
                                                    V, F, C);
  }
}

// Round 7
// 187.361 us; speedup vs baseline: 18.6581x; 1.4274x over previous
//
#include <hip/hip_runtime.h>

#define HPIX 256
#define WPIX 256
#define TSX 16
#define TSY 16
#define NTILE 256            // 16x16 tiles of 16x16 px
#define FCH 256
#define SEG_FLAT 16          // segments over all faces (fallback path)
#define NBUCK 4096           // minz counting-sort buckets over [1,2)
#define RSEG 8               // waves (bin segments) per quadrant block
#define BIGF 1000000000.0f
#define EPSF 1e-8f
#define MARGIN 0.125f
#define HP_SLOP 0.0625f      // >= 4x the FP eval error bound (~0.015 w-units)
#define EPSZ 1e-4f           // early-exit slack >> depth/minz FP error (~2e-6)
#define INIT_PACK 0xFFFFFFFFFFFFFFFFull

struct FaceRec {
  float x2, y2, a0, b0, a1, b1, inv, z0, z1, z2;
  float xmin, ymin, xmax, ymax;
};

// Compute the per-face record with EXACTLY the reference's op order (no FMA).
__device__ __forceinline__ FaceRec make_rec(const float* __restrict__ vb,
                                            const int* __restrict__ faces, int f) {
#pragma clang fp contract(off)
  FaceRec r;
  int i0 = faces[f * 3 + 0], i1 = faces[f * 3 + 1], i2 = faces[f * 3 + 2];
  float x0 = vb[i0 * 3 + 0], y0 = vb[i0 * 3 + 1], z0 = vb[i0 * 3 + 2];
  float x1 = vb[i1 * 3 + 0], y1 = vb[i1 * 3 + 1], z1 = vb[i1 * 3 + 2];
  float x2 = vb[i2 * 3 + 0], y2 = vb[i2 * 3 + 1], z2 = vb[i2 * 3 + 2];
  float px0 = x0 / z0, py0 = y0 / z0;
  float px1 = x1 / z1, py1 = y1 / z1;
  float px2 = x2 / z2, py2 = y2 / z2;
  float a0 = py1 - py2, b0 = px2 - px1;   // (y1-y2), (x2-x1)
  float a1 = py2 - py0, b1 = px0 - px2;   // (y2-y0), (x0-x2)
  float dy02 = py0 - py2;
  float denom = a0 * b1 + b0 * dy02;      // (y1-y2)*(x0-x2) + (x2-x1)*(y0-y2)
  bool nz = fabsf(denom) > EPSF;
  bool valid = nz && (z0 > 0.0f) && (z1 > 0.0f) && (z2 > 0.0f);
  r.x2 = px2; r.y2 = py2; r.a0 = a0; r.b0 = b0; r.a1 = a1; r.b1 = b1;
  r.inv = valid ? 1.0f / denom : 0.0f;
  r.z0 = z0; r.z1 = z1;
  r.z2 = valid ? z2 : -1.0f;              // invalid -> depth<0 -> fails depth>0
  if (valid) {
    r.xmin = fminf(px0, fminf(px1, px2)) - MARGIN;
    r.xmax = fmaxf(px0, fmaxf(px1, px2)) + MARGIN;
    r.ymin = fminf(py0, fminf(py1, py2)) - MARGIN;
    r.ymax = fmaxf(py0, fmaxf(py1, py2)) + MARGIN;
  } else {
    r.xmin = 2.0f * BIGF; r.xmax = -2.0f * BIGF;
    r.ymin = 2.0f * BIGF; r.ymax = -2.0f * BIGF;
  }
  return r;
}

// Same arithmetic as make_rec for the validity flag + minz (must match exactly).
__device__ __forceinline__ void classify(const float* __restrict__ vb,
                                         const int* __restrict__ faces, int f,
                                         bool& valid, float& minz) {
#pragma clang fp contract(off)
  int i0 = faces[f * 3 + 0], i1 = faces[f * 3 + 1], i2 = faces[f * 3 + 2];
  float x0 = vb[i0 * 3 + 0], y0 = vb[i0 * 3 + 1], z0 = vb[i0 * 3 + 2];
  float x1 = vb[i1 * 3 + 0], y1 = vb[i1 * 3 + 1], z1 = vb[i1 * 3 + 2];
  float x2 = vb[i2 * 3 + 0], y2 = vb[i2 * 3 + 1], z2 = vb[i2 * 3 + 2];
  float px0 = x0 / z0, py0 = y0 / z0;
  float px1 = x1 / z1, py1 = y1 / z1;
  float px2 = x2 / z2, py2 = y2 / z2;
  float a0 = py1 - py2, b0 = px2 - px1;
  float b1 = px0 - px2;
  float dy02 = py0 - py2;
  float denom = a0 * b1 + b0 * dy02;
  bool nz = fabsf(denom) > EPSF;
  valid = nz && (z0 > 0.0f) && (z1 > 0.0f) && (z2 > 0.0f);
  minz = fminf(z0, fminf(z1, z2));
}

// ---------- sorted path ----------
__global__ void zero_hist_kernel(unsigned int* __restrict__ hist, int n) {
  int i = blockIdx.x * blockDim.x + threadIdx.x;
  if (i < n) hist[i] = 0u;
}

__global__ void key_hist_kernel(const float* __restrict__ verts,
                                const int* __restrict__ faces,
                                unsigned int* __restrict__ keys,
                                unsigned int* __restrict__ hist,
                                int V, int F, int NIMG) {
  int idx = blockIdx.x * blockDim.x + threadIdx.x;
  if (idx >= NIMG * F) return;
  int n = idx / F, f = idx - n * F;
  bool valid; float minz;
  classify(verts + (size_t)n * V * 3, faces, f, valid, minz);
  int b;
  if (!valid) b = NBUCK - 1;
  else {
    float t = (minz - 1.0f) * (float)NBUCK;
    b = (int)floorf(t);
    b = b < 0 ? 0 : (b > NBUCK - 1 ? NBUCK - 1 : b);
  }
  keys[idx] = (unsigned int)b;
  atomicAdd(&hist[n * NBUCK + b], 1u);
}

__global__ __launch_bounds__(1024) void scan_kernel(unsigned int* __restrict__ hist) {
  __shared__ unsigned int s[1024];
  unsigned int* h = hist + (size_t)blockIdx.x * NBUCK;
  int t = threadIdx.x;
  unsigned int v0 = h[4 * t], v1 = h[4 * t + 1], v2 = h[4 * t + 2], v3 = h[4 * t + 3];
  unsigned int sum = v0 + v1 + v2 + v3;
  s[t] = sum;
  __syncthreads();
  for (int off = 1; off < 1024; off <<= 1) {
    unsigned int x = (t >= off) ? s[t - off] : 0u;
    __syncthreads();
    s[t] += x;
    __syncthreads();
  }
  unsigned int excl = s[t] - sum;
  h[4 * t] = excl;
  h[4 * t + 1] = excl + v0;
  h[4 * t + 2] = excl + v0 + v1;
  h[4 * t + 3] = excl + v0 + v1 + v2;
}

// Scatter recs into minz-bucket-sorted order. o[2].z = key_lo (round-down
// bucket bound, <= true minz); o[2].w = original face id (bit transport).
__global__ void scatter_kernel(const float* __restrict__ verts,
                               const int* __restrict__ faces,
                               const unsigned int* __restrict__ keys,
                               unsigned int* __restrict__ hist,
                               float4* __restrict__ srecs,
                               int V, int F, int NIMG) {
  int idx = blockIdx.x * blockDim.x + threadIdx.x;
  if (idx >= NIMG * F) return;
  int n = idx / F, f = idx - n * F;
  const float* vb = verts + (size_t)n * V * 3;
  FaceRec r = make_rec(vb, faces, f);
  bool valid; float minz;
  classify(vb, faces, f, valid, minz);
  unsigned int b = keys[idx];
  // bucket 0 uses a sentinel so minz<1 robustness can't cause early-exit bugs
  float key_lo = (b == 0u) ? -3.0e38f
               : fminf(1.0f + (float)b * (1.0f / (float)NBUCK),
                       valid ? minz : 3.0e38f);
  unsigned int pos = atomicAdd(&hist[n * NBUCK + b], 1u);
  float4* o = srecs + ((size_t)n * F + pos) * 4;
  o[0] = make_float4(r.x2, r.y2, r.a0, r.b0);
  o[1] = make_float4(r.a1, r.b1, r.inv, r.z0);
  o[2] = make_float4(r.z1, r.z2, key_lo, __int_as_float(f));
  o[3] = make_float4(r.xmin, r.ymin, r.xmax, r.ymax);
}

// Order-preserving binning: iterate sorted positions j in chunks of 256;
// block-ordered compaction keeps each bin ascending in j (=> ascending key_lo).
__global__ __launch_bounds__(256) void bin_kernel(
    const float4* __restrict__ srecs, unsigned int* __restrict__ cursors,
    unsigned int* __restrict__ bins, int F) {
#pragma clang fp contract(off)
  const int t = blockIdx.x, n = blockIdx.y;
  const int tlx = t & 15, tly = t >> 4;
  const float X0 = (float)(tlx * TSX), X1 = X0 + (float)(TSX - 1);
  const float Y0 = (float)(tly * TSY), Y1 = Y0 + (float)(TSY - 1);
  __shared__ unsigned int s_cnt[4];
  __shared__ unsigned int s_cur;
  const int tid = (int)threadIdx.x;
  const int lane = tid & 63, wid = tid >> 6;
  if (tid == 0) s_cur = 0u;
  __syncthreads();
  const float4* rb = srecs + (size_t)n * F * 4;
  unsigned int* bin = bins + ((size_t)(n * NTILE + t)) * F;
  for (int base = 0; base < F; base += 256) {
    int j = base + tid;
    bool keep = false;
    if (j < F) {
      float4 D = rb[j * 4 + 3];
      keep = (D.x <= X1) && (D.z >= X0) && (D.y <= Y1) && (D.w >= Y0);
      if (keep) {
        float4 A = rb[j * 4 + 0];
        float4 B = rb[j * 4 + 1];
        float inv = B.z;
        if (fabsf(inv) <= 1.0f) {
          float m0 = -3.0e38f, m1 = -3.0e38f, m2 = -3.0e38f;
#pragma unroll
          for (int c = 0; c < 4; ++c) {
            float ccx = (c & 1) ? X1 : X0;
            float ccy = (c & 2) ? Y1 : Y0;
            float bx = ccx - A.x, by = ccy - A.y;
            float w0 = (A.z * bx + A.w * by) * inv;
            float w1 = (B.x * bx + B.y * by) * inv;
            float w2 = 1.0f - w0 - w1;
            m0 = fmaxf(m0, w0); m1 = fmaxf(m1, w1); m2 = fmaxf(m2, w2);
          }
          keep = (m0 >= -HP_SLOP) && (m1 >= -HP_SLOP) && (m2 >= -HP_SLOP);
        }
      }
    }
    unsigned long long m = __ballot(keep);
    int cw = __popcll(m);
    if (lane == 0) s_cnt[wid] = (unsigned int)cw;
    __syncthreads();
    unsigned int woff = s_cur;
    for (int w = 0; w < wid; ++w) woff += s_cnt[w];
    unsigned int tot = s_cnt[0] + s_cnt[1] + s_cnt[2] + s_cnt[3];
    if (keep) {
      int off = __popcll(m & ((1ull << lane) - 1ull));
      bin[woff + (unsigned int)off] = (unsigned int)j;
    }
    __syncthreads();             // all reads of s_cur/s_cnt done
    if (tid == 0) s_cur += tot;
  }
  __syncthreads();
  if (tid == 0) cursors[n * NTILE + t] = s_cur;
}

// Epilogue: interpolate colors for the winning face, apply any-positive mask,
// write NCHW. Recomputes weights via make_rec -> bit-identical values.
__device__ __forceinline__ void emit_pixel(float* __restrict__ out,
    const float* __restrict__ vb, const float* __restrict__ colors,
    const int* __restrict__ faces, int n, int V, int C, int bestf,
    float cx, float cy, int row, int col) {
#pragma clang fp contract(off)
  float cv[8];
#pragma unroll
  for (int ch = 0; ch < 8; ++ch) cv[ch] = 0.0f;
  if (bestf >= 0) {
    int i0 = faces[bestf * 3 + 0], i1 = faces[bestf * 3 + 1], i2 = faces[bestf * 3 + 2];
    FaceRec r = make_rec(vb, faces, bestf);
    float bx = cx - r.x2, by = cy - r.y2;
    float w0 = (r.a0 * bx + r.b0 * by) * r.inv;
    float w1 = (r.a1 * bx + r.b1 * by) * r.inv;
    float w2 = 1.0f - w0 - w1;
    const float* c0 = colors + ((size_t)n * V + i0) * C;
    const float* c1 = colors + ((size_t)n * V + i1) * C;
    const float* c2 = colors + ((size_t)n * V + i2) * C;
    for (int ch = 0; ch < C && ch < 8; ++ch)
      cv[ch] = (w0 * c0[ch] + w1 * c1[ch]) + w2 * c2[ch];
  }
  bool anyp = false;
  for (int ch = 0; ch < C && ch < 8; ++ch) anyp = anyp || (cv[ch] > 0.0f);
  float m = anyp ? 1.0f : 0.0f;
  size_t base = (size_t)n * C * HPIX * WPIX + (size_t)row * WPIX + col;
  for (int ch = 0; ch < C && ch < 8; ++ch)
    out[base + (size_t)ch * HPIX * WPIX] = cv[ch] * m;
}

#define TESTF(Ak, Bk, Zk)                                                     \
  {                                                                           \
    float bx = cx - Ak.x, by = cy - Ak.y;                                     \
    float w0 = (Ak.z * bx + Ak.w * by) * Bk.z;                                \
    float w1 = (Bk.x * bx + Bk.y * by) * Bk.z;                                \
    float w2 = 1.0f - w0 - w1;                                                \
    float depth = (w0 * Bk.w + w1 * Zk.x) + w2 * Zk.y;                        \
    bool ok = (w0 >= 0.0f) && (w1 >= 0.0f) && (w2 >= 0.0f) && (depth > 0.0f); \
    if (ok) {                                                                 \
      unsigned int forig = (unsigned int)__float_as_int(Zk.w);                \
      unsigned long long p =                                                  \
          ((unsigned long long)__float_as_uint(depth) << 32) | forig;         \
      if (p < best) best = p;                                                 \
    }                                                                         \
  }

// 512 threads = 8 waves per 8x8 quadrant; wave w scans sorted subsequence
// {w, w+RSEG, ...}. BLOCK-SHARED depth cut: sdmin[lane] holds the packed
// (depth,face) running min per pixel across ALL waves (lane->pixel mapping is
// identical in every wave). Each wave reads it for the exit check and flushes
// improvements via LDS atomicMin. Pruning with the shared cut is safe: a
// skipped face has depth >= key_lo - 2e-6 > dcut >= final depth, so it loses
// strictly (min and index tie-break unchanged). sdmin doubles as the final
// cross-wave reduction.
__global__ __launch_bounds__(512) void raster_sorted(
    const float4* __restrict__ srecs, const unsigned int* __restrict__ bins,
    const unsigned int* __restrict__ cursors, const float* __restrict__ verts,
    const float* __restrict__ colors, const int* __restrict__ faces,
    float* __restrict__ out, int V, int F, int C) {
#pragma clang fp contract(off)
  __shared__ unsigned long long sdmin[64];
  const int bq = blockIdx.x;
  const int t = bq >> 2, quad = bq & 3;
  const int n = blockIdx.y;
  const int tlx = t & 15, tly = t >> 4;
  const int tid = (int)threadIdx.x;
  const int wave = tid >> 6, lane = tid & 63;
  const int tx = lane & 7, ty = lane >> 3;
  const int col = tlx * TSX + (quad & 1) * 8 + tx;
  const int row = tly * TSY + (quad >> 1) * 8 + ty;
  const float cx = (float)col, cy = (float)row;
  const float4* rb = srecs + (size_t)n * F * 4;
  const unsigned int* bin = bins + ((size_t)(n * NTILE + t)) * F;
  const int cnt = (int)cursors[n * NTILE + t];
  if (tid < 64) sdmin[tid] = INIT_PACK;
  __syncthreads();
  unsigned long long best = INIT_PACK;
  unsigned long long written = INIT_PACK;
  const int stride = 4 * RSEG;
  int i0 = wave;
  int j0 = 0, j1 = 0, j2 = 0, j3 = 0;
  if (i0 < cnt) {
    int c1i = i0 + RSEG     < cnt ? i0 + RSEG     : cnt - 1;
    int c2i = i0 + 2 * RSEG < cnt ? i0 + 2 * RSEG : cnt - 1;
    int c3i = i0 + 3 * RSEG < cnt ? i0 + 3 * RSEG : cnt - 1;
    j0 = (int)bin[i0]; j1 = (int)bin[c1i]; j2 = (int)bin[c2i]; j3 = (int)bin[c3i];
  }
  for (; i0 < cnt; i0 += stride) {
    // prefetch next batch's bin indices (removes one dependent round-trip)
    int ni = i0 + stride;
    int nj0 = 0, nj1 = 0, nj2 = 0, nj3 = 0;
    if (ni < cnt) {
      int d1 = ni + RSEG     < cnt ? ni + RSEG     : cnt - 1;
      int d2 = ni + 2 * RSEG < cnt ? ni + 2 * RSEG : cnt - 1;
      int d3 = ni + 3 * RSEG < cnt ? ni + 3 * RSEG : cnt - 1;
      nj0 = (int)bin[ni]; nj1 = (int)bin[d1]; nj2 = (int)bin[d2]; nj3 = (int)bin[d3];
    }
    float4 Z0 = rb[j0 * 4 + 2], Z1 = rb[j1 * 4 + 2];
    float4 Z2 = rb[j2 * 4 + 2], Z3 = rb[j3 * 4 + 2];
    float4 A0 = rb[j0 * 4 + 0], B0 = rb[j0 * 4 + 1];
    float4 A1 = rb[j1 * 4 + 0], B1 = rb[j1 * 4 + 1];
    float4 A2 = rb[j2 * 4 + 0], B2 = rb[j2 * 4 + 1];
    float4 A3 = rb[j3 * 4 + 0], B3 = rb[j3 * 4 + 1];
    // shared per-pixel depth cut (lags by at most one flush; only shrinks)
    unsigned long long sh = sdmin[lane];
    float dcut = __uint_as_float((unsigned int)(sh >> 32));  // NaN if INIT
    if (__all(Z0.z > dcut + EPSZ)) break;   // sorted: all later faces deeper
    TESTF(A0, B0, Z0);
    if (i0 + RSEG < cnt)     TESTF(A1, B1, Z1);
    if (i0 + 2 * RSEG < cnt) TESTF(A2, B2, Z2);
    if (i0 + 3 * RSEG < cnt) TESTF(A3, B3, Z3);
    if (best < written) { atomicMin(&sdmin[lane], best); written = best; }
    j0 = nj0; j1 = nj1; j2 = nj2; j3 = nj3;
  }
  if (best < written) atomicMin(&sdmin[lane], best);
  __syncthreads();
  if (tid < 64) {
    unsigned long long b = sdmin[lane];
    int bestf = (b == INIT_PACK) ? -1 : (int)(unsigned int)(b & 0xFFFFFFFFull);
    emit_pixel(out, verts + (size_t)n * V * 3, colors, faces, n, V, C, bestf,
               cx, cy, row, col);
  }
}

// ---------- fallbacks (smaller ws) ----------
__global__ void prep_kernel(const float* __restrict__ verts,
                            const int* __restrict__ faces,
                            float4* __restrict__ recs, int V, int F, int NIMG) {
  int idx = blockIdx.x * blockDim.x + threadIdx.x;
  int total = NIMG * F;
  if (idx >= total) return;
  int n = idx / F, f = idx - n * F;
  FaceRec r = make_rec(verts + (size_t)n * V * 3, faces, f);
  float4* o = recs + (size_t)idx * 4;
  o[0] = make_float4(r.x2, r.y2, r.a0, r.b0);
  o[1] = make_float4(r.a1, r.b1, r.inv, r.z0);
  o[2] = make_float4(r.z1, r.z2, 0.0f, 0.0f);
  o[3] = make_float4(r.xmin, r.ymin, r.xmax, r.ymax);
}

__global__ void init_kernel(unsigned long long* __restrict__ packed, int npix) {
  int i = blockIdx.x * blockDim.x + threadIdx.x;
  if (i < npix) packed[i] = INIT_PACK;
}

__device__ __forceinline__ void test_face(float4 A, float4 B, float4 Z, int f,
                                          float cx, float cy,
                                          unsigned long long& best) {
#pragma clang fp contract(off)
  float bx = cx - A.x, by = cy - A.y;
  float w0 = (A.z * bx + A.w * by) * B.z;
  float w1 = (B.x * bx + B.y * by) * B.z;
  float w2 = 1.0f - w0 - w1;
  float depth = (w0 * B.w + w1 * Z.x) + w2 * Z.y;
  bool ok = (w0 >= 0.0f) && (w1 >= 0.0f) && (w2 >= 0.0f) && (depth > 0.0f);
  if (ok) {
    unsigned long long p =
        ((unsigned long long)__float_as_uint(depth) << 32) | (unsigned int)f;
    best = p < best ? p : best;
  }
}

__global__ __launch_bounds__(256) void raster_seg(
    const float4* __restrict__ recs, unsigned long long* __restrict__ packed,
    int F) {
  const int tx = threadIdx.x, ty = threadIdx.y;
  const int n = blockIdx.z / SEG_FLAT, s = blockIdx.z % SEG_FLAT;
  const int col = blockIdx.x * TSX + tx, row = blockIdx.y * TSY + ty;
  const float cx = (float)col, cy = (float)row;
  const float tX0 = (float)(blockIdx.x * TSX), tX1 = tX0 + (float)(TSX - 1);
  const float tY0 = (float)(blockIdx.y * TSY), tY1 = tY0 + (float)(TSY - 1);
  const float4* rb = recs + (size_t)n * F * 4;
  unsigned long long best = INIT_PACK;
  for (int f = s; f < F; f += SEG_FLAT) {
    float4 bb = rb[f * 4 + 3];
    if (bb.x > tX1 || bb.z < tX0 || bb.y > tY1 || bb.w < tY0) continue;
    float4 A = rb[f * 4 + 0];
    float4 B = rb[f * 4 + 1];
    float4 Z = rb[f * 4 + 2];
    test_face(A, B, Z, f, cx, cy, best);
  }
  if (best != INIT_PACK)
    atomicMin(&packed[(size_t)n * (HPIX * WPIX) + row * WPIX + col], best);
}

__global__ __launch_bounds__(256) void resolve_kernel(
    const unsigned long long* __restrict__ packed,
    const float* __restrict__ verts, const float* __restrict__ colors,
    const int* __restrict__ faces, float* __restrict__ out,
    int V, int F, int C, int NIMG) {
  int i = blockIdx.x * blockDim.x + threadIdx.x;
  int total = NIMG * HPIX * WPIX;
  if (i >= total) return;
  int n = i / (HPIX * WPIX);
  int pix = i - n * (HPIX * WPIX);
  int row = pix >> 8, col = pix & 255;
  unsigned long long p = packed[i];
  int bestf = (p == INIT_PACK) ? -1 : (int)(unsigned int)(p & 0xFFFFFFFFull);
  emit_pixel(out, verts + (size_t)n * V * 3, colors, faces, n, V, C, bestf,
             (float)col, (float)row, row, col);
}

__global__ __launch_bounds__(256) void raster_l(const float* __restrict__ verts,
    const float* __restrict__ colors, const int* __restrict__ faces,
    float* __restrict__ out, int V, int F, int C) {
#pragma clang fp contract(off)
  __shared__ float4 sA[FCH], sB[FCH], sZ[FCH], sD[FCH];
  const int n = blockIdx.z;
  const int tx = threadIdx.x, ty = threadIdx.y;
  const int tid = ty * TSX + tx;
  const int col = blockIdx.x * TSX + tx;
  const int row = blockIdx.y * TSY + ty;
  const float cx = (float)col, cy = (float)row;
  const float tX0 = (float)(blockIdx.x * TSX), tX1 = tX0 + (float)(TSX - 1);
  const float tY0 = (float)(blockIdx.y * TSY), tY1 = tY0 + (float)(TSY - 1);
  const float* vb = verts + (size_t)n * V * 3;
  float bestd = BIGF;
  int bestf = -1;
  for (int base = 0; base < F; base += FCH) {
    int cnt = min(FCH, F - base);
    if (tid < cnt) {
      FaceRec r = make_rec(vb, faces, base + tid);
      sA[tid] = make_float4(r.x2, r.y2, r.a0, r.b0);
      sB[tid] = make_float4(r.a1, r.b1, r.inv, r.z0);
      sZ[tid] = make_float4(r.z1, r.z2, 0.0f, 0.0f);
      sD[tid] = make_float4(r.xmin, r.ymin, r.xmax, r.ymax);
    }
    __syncthreads();
    for (int j = 0; j < cnt; ++j) {
      float4 bb = sD[j];
      if (bb.x > tX1 || bb.z < tX0 || bb.y > tY1 || bb.w < tY0) continue;
      float4 A = sA[j];
      float4 B = sB[j];
      float4 Z = sZ[j];
      float bx = cx - A.x, by = cy - A.y;
      float w0 = (A.z * bx + A.w * by) * B.z;
      float w1 = (B.x * bx + B.y * by) * B.z;
      float w2 = 1.0f - w0 - w1;
      float depth = (w0 * B.w + w1 * Z.x) + w2 * Z.y;
      bool ok = (w0 >= 0.0f) && (w1 >= 0.0f) && (w2 >= 0.0f) && (depth > 0.0f);
      float d = ok ? depth : BIGF;
      if (d < bestd) { bestd = d; bestf = base + j; }
    }
    __syncthreads();
  }
  emit_pixel(out, vb, colors, faces, n, V, C, bestf, cx, cy, row, col);
}

extern "C" void kernel_launch(void* const* d_in, const int* in_sizes, int n_in,
                              void* d_out, int out_size, void* d_ws, size_t ws_size,
                              hipStream_t stream) {
  const float* verts = (const float*)d_in[0];
  const float* colors = (const float*)d_in[1];
  const int* faces = (const int*)d_in[2];
  float* out = (float*)d_out;
  long long s0 = in_sizes[0], s1 = in_sizes[1], s2 = in_sizes[2];
  int C = (int)((3LL * s1) / s0);
  if (C < 1) C = 1;
  int NC = out_size / (HPIX * WPIX);
  int N = NC / C;
  if (N < 1) N = 1;
  int V = (int)(s0 / (3LL * N));
  int F = (int)(s2 / 3);

  // sorted-path ws layout: srecs | keys | hist | cursors | bins
  size_t offS = 0;
  size_t szS = (size_t)N * F * 4 * sizeof(float4);
  size_t offK = (offS + szS + 255) & ~(size_t)255;
  size_t szK = (size_t)N * F * sizeof(unsigned int);
  size_t offH = (offK + szK + 255) & ~(size_t)255;
  size_t szH = (size_t)N * NBUCK * sizeof(unsigned int);
  size_t offC2 = (offH + szH + 255) & ~(size_t)255;
  size_t szC2 = (size_t)N * NTILE * sizeof(unsigned int);
  size_t offB2 = (offC2 + szC2 + 255) & ~(size_t)255;
  size_t szB2 = (size_t)N * NTILE * (size_t)F * sizeof(unsigned int);
  size_t need_sorted = offB2 + szB2;

  // fallback layout: recs | packed
  size_t szR = (size_t)N * F * 4 * sizeof(float4);
  size_t offP = (szR + 255) & ~(size_t)255;
  size_t szP = (size_t)N * HPIX * WPIX * sizeof(unsigned long long);

  dim3 block(TSX, TSY);
  char* ws = (char*)d_ws;
  int total = N * F;
  int npix = N * HPIX * WPIX;

  if (d_ws != nullptr && ws_size >= need_sorted) {
    float4* srecs = (float4*)(ws + offS);
    unsigned int* keys = (unsigned int*)(ws + offK);
    unsigned int* hist = (unsigned int*)(ws + offH);
    unsigned int* cursors = (unsigned int*)(ws + offC2);
    unsigned int* bins = (unsigned int*)(ws + offB2);
    int nh = N * NBUCK;
    zero_hist_kernel<<<(nh + 255) / 256, 256, 0, stream>>>(hist, nh);
    key_hist_kernel<<<(total + 255) / 256, 256, 0, stream>>>(verts, faces, keys,
                                                             hist, V, F, N);
    scan_kernel<<<N, 1024, 0, stream>>>(hist);
    scatter_kernel<<<(total + 255) / 256, 256, 0, stream>>>(verts, faces, keys,
                                                            hist, srecs, V, F, N);
    bin_kernel<<<dim3(NTILE, N), 256, 0, stream>>>(srecs, cursors, bins, F);
    raster_sorted<<<dim3(NTILE * 4, N), 512, 0, stream>>>(srecs, bins, cursors,
                                                          verts, colors, faces,
                                                          out, V, F, C);
  } else if (d_ws != nullptr && ws_size >= offP + szP) {
    float4* recs = (float4*)ws;
    unsigned long long* packed = (unsigned long long*)(ws + offP);
    init_kernel<<<(npix + 255) / 256, 256, 0, stream>>>(packed, npix);
    prep_kernel<<<(total + 255) / 256, 256, 0, stream>>>(verts, faces, recs, V, F, N);
    raster_seg<<<dim3(16, 16, N * SEG_FLAT), block, 0, stream>>>(recs, packed, F);
    resolve_kernel<<<(npix + 255) / 256, 256, 0, stream>>>(packed, verts, colors,
                                                           faces, out, V, F, C, N);
  } else {
    raster_l<<<dim3(16, 16, N), block, 0, stream>>>(verts, colors, faces, out,
                                                    V, F, C);
  }
}